// Round 8
// baseline (1047.557 us; speedup 1.0000x reference)
//
#include <hip/hip_runtime.h>
#include <math.h>

#define BB 2048
#define SS 96
#define DD 7
#define HH 64
#define H2 16
#define LSTR 68    // loB row stride (fp32): 68*4=272B = 17*16 -> b128-aligned rows
#define HSTR 104   // f16 tile row stride: 104*2=208B = 13*16 -> b128-aligned rows

typedef _Float16 f16x8 __attribute__((ext_vector_type(8)));
typedef float f32x4 __attribute__((ext_vector_type(4)));

__device__ __forceinline__ float sigm(float x) { return 1.0f / (1.0f + __expf(-x)); }
__device__ __forceinline__ float tanh_f(float x) { return 1.0f - 2.0f / (__expf(2.0f * x) + 1.0f); }
__device__ __forceinline__ float rl(float v, int l) {
    return __int_as_float(__builtin_amdgcn_readlane(__float_as_int(v), l));
}
// load 8 consecutive fp32 (16B-aligned) and convert to an f16x8 A/B fragment
__device__ __forceinline__ f16x8 frag_from_f32(const float* base) {
    const float4* p = (const float4*)base;
    float4 a = p[0], b = p[1];
    f16x8 r;
    r[0] = (_Float16)a.x; r[1] = (_Float16)a.y; r[2] = (_Float16)a.z; r[3] = (_Float16)a.w;
    r[4] = (_Float16)b.x; r[5] = (_Float16)b.y; r[6] = (_Float16)b.z; r[7] = (_Float16)b.w;
    return r;
}

// ---------------- Kernel 1: feature attention (unchanged) ----------------
__global__ __launch_bounds__(256) void k_feat(
    const float* __restrict__ x,
    const float* __restrict__ fv_w, const float* __restrict__ fv_b,
    const float* __restrict__ fk_w, const float* __restrict__ fk_b,
    const float* __restrict__ fq_w, const float* __restrict__ fq_b,
    float* __restrict__ fa_out)
{
    __shared__ float xs[SS * DD], vs[SS * DD], ks[SS * DD], qs[SS * DD];
    __shared__ float att[DD * DD];
    __shared__ float wv[DD * DD], wk[DD * DD], wq[DD * DD];
    __shared__ float bv[DD], bk[DD], bq[DD];
    const int b = blockIdx.x, t = threadIdx.x;
    const float* xb = x + (size_t)b * SS * DD;

    for (int idx = t; idx < SS * DD; idx += 256) xs[idx] = xb[idx];
    if (t < DD * DD) { wv[t] = fv_w[t]; wk[t] = fk_w[t]; wq[t] = fq_w[t]; }
    if (t < DD)      { bv[t] = fv_b[t]; bk[t] = fk_b[t]; bq[t] = fq_b[t]; }
    __syncthreads();

    for (int idx = t; idx < SS * DD; idx += 256) {
        int s = idx / DD, j = idx % DD;
        float a = bv[j];
        #pragma unroll
        for (int i = 0; i < DD; i++) a += xs[s * DD + i] * wv[j * DD + i];
        vs[idx] = a;
    }
    __syncthreads();
    for (int idx = t; idx < SS * DD; idx += 256) {
        int s = idx / DD, j = idx % DD;
        float a = bk[j];
        #pragma unroll
        for (int i = 0; i < DD; i++) a += (xs[s * DD + i] + vs[s * DD + i]) * wk[j * DD + i];
        ks[idx] = a;
    }
    __syncthreads();
    for (int idx = t; idx < SS * DD; idx += 256) {
        int s = idx / DD, j = idx % DD;
        float a = bq[j];
        #pragma unroll
        for (int i = 0; i < DD; i++) a += (xs[s * DD + i] + ks[s * DD + i]) * wq[j * DD + i];
        qs[idx] = a;
    }
    __syncthreads();
    if (t < DD * DD) {
        int i = t / DD, j = t % DD;
        float a = 0.0f;
        for (int s = 0; s < SS; s++) a += qs[s * DD + i] * ks[s * DD + j];
        att[t] = a;
    }
    __syncthreads();
    if (t < DD) {
        float m = -1e30f;
        #pragma unroll
        for (int j = 0; j < DD; j++) m = fmaxf(m, att[t * DD + j]);
        float e[DD]; float sum = 0.0f;
        #pragma unroll
        for (int j = 0; j < DD; j++) { e[j] = __expf(att[t * DD + j] - m); sum += e[j]; }
        float inv = 1.0f / sum;
        #pragma unroll
        for (int j = 0; j < DD; j++) att[t * DD + j] = e[j] * inv;
    }
    __syncthreads();
    for (int idx = t; idx < SS * DD; idx += 256) {
        int s = idx / DD, j = idx % DD;
        float a = xs[idx];
        #pragma unroll
        for (int i = 0; i < DD; i++) a += vs[s * DD + i] * att[i * DD + j];
        fa_out[(size_t)b * SS * DD + idx] = tanh_f(a);
    }
}

// ---------------- Kernel 2: bidirectional LSTM ----------------
// launch_bounds(512,1): 1 block/CU -> 256-VGPR budget so wr[64] stays resident.
// volatile W_hh loads: non-rematerializable -> regalloc must keep them live.
__global__ __launch_bounds__(512, 1) void k_bilstm(
    const float* __restrict__ fa,
    const float* __restrict__ wih_f, const float* __restrict__ whh_f,
    const float* __restrict__ bih_f, const float* __restrict__ bhh_f,
    const float* __restrict__ wih_b, const float* __restrict__ whh_b,
    const float* __restrict__ bih_b, const float* __restrict__ bhh_b,
    float* __restrict__ lo_out)
{
    __shared__ float fas[SS * DD];
    __shared__ float hbuf[2][HH];
    __shared__ float hs[2][SS][HH];

    const int b = blockIdx.x, t = threadIdx.x;
    const int lane = t & 63, w = t >> 6;
    const int dir = w >> 2, wq4 = w & 3;
    const int u = lane & 15;
    const int gi = lane >> 4;
    const int unit = 16 * wq4 + u;
    const int row = 64 * gi + unit;

    for (int idx = t; idx < SS * DD; idx += 512) fas[idx] = fa[(size_t)b * SS * DD + idx];

    const volatile float* whh = dir ? whh_b : whh_f;   // volatile: force VGPR residency
    const float* wih = dir ? wih_b : wih_f;
    float wr[HH];
    #pragma unroll
    for (int j = 0; j < HH; j++) wr[j] = whh[row * HH + j];
    float wx[DD];
    #pragma unroll
    for (int i = 0; i < DD; i++) wx[i] = wih[row * DD + i];
    const float bias = dir ? (bih_b[row] + bhh_b[row]) : (bih_f[row] + bhh_f[row]);

    if (t < 128) hbuf[t >> 6][t & 63] = 0.0f;
    __syncthreads();

    float c = 0.0f;
    for (int step = 0; step < SS; step++) {
        const int s = dir ? (SS - 1 - step) : step;
        float freg = fas[s * DD + (lane < DD ? lane : DD - 1)];
        float a = bias;
        #pragma unroll
        for (int i = 0; i < DD; i++) a += rl(freg, i) * wx[i];
        float hreg = hbuf[dir][lane];
        float b0 = 0.f, b1 = 0.f, b2 = 0.f, b3 = 0.f;
        #pragma unroll
        for (int j = 0; j < HH; j += 4) {
            b0 += rl(hreg, j)     * wr[j];
            b1 += rl(hreg, j + 1) * wr[j + 1];
            b2 += rl(hreg, j + 2) * wr[j + 2];
            b3 += rl(hreg, j + 3) * wr[j + 3];
        }
        a += (b0 + b1) + (b2 + b3);
        float iv = __shfl(a, u);
        float fv = __shfl(a, 16 + u);
        float gv = __shfl(a, 32 + u);
        float ov = __shfl(a, 48 + u);
        c = sigm(fv) * c + sigm(iv) * tanh_f(gv);
        float h = sigm(ov) * tanh_f(c);
        if (gi == 0) {
            hbuf[dir][unit] = h;
            hs[dir][s][unit] = h;
        }
        __syncthreads();
    }

    for (int idx = t; idx < SS * HH; idx += 512) {
        int s = idx >> 6, j = idx & 63;
        lo_out[(size_t)b * SS * HH + idx] = 0.5f * (hs[0][s][j] + hs[1][s][j]);
    }
}

// ---------------- Kernel 3: temporal attention via MFMA f16 + LSTM2 + fc (unchanged) ----------------
__global__ __launch_bounds__(512, 2) void k_temporal(
    const float* __restrict__ lo_g,
    const float* __restrict__ tv_w, const float* __restrict__ tv_b,
    const float* __restrict__ tk_w, const float* __restrict__ tk_b,
    const float* __restrict__ tq_w, const float* __restrict__ tq_b,
    const float* __restrict__ l2_wih, const float* __restrict__ l2_whh,
    const float* __restrict__ l2_bih, const float* __restrict__ l2_bhh,
    const float* __restrict__ fc_w, const float* __restrict__ fc_b,
    float* __restrict__ out)
{
    __shared__ float loB[SS * LSTR];        // lo -> 'to' -> xg2
    __shared__ _Float16 qB[SS * HSTR];      // q[s][f]; later p[s][P]
    __shared__ _Float16 tkS[SS * HSTR];     // tk[s][f]
    __shared__ _Float16 tvT[HH * HSTR];     // tv^T[d][P]; later hsb fp32[96*17]

    const int b = blockIdx.x, t = threadIdx.x;
    const int lane = t & 63, w = t >> 6;
    const int col = lane & 15, quad = lane >> 4;

    const float4* lo_src = (const float4*)(lo_g + (size_t)b * SS * HH);
    #pragma unroll
    for (int k = 0; k < 3; k++) {
        int idx4 = t + 512 * k;
        float4 v = lo_src[idx4];
        int s = idx4 >> 4, d = (idx4 & 15) * 4;
        loB[s * LSTR + d]     = v.x;
        loB[s * LSTR + d + 1] = v.y;
        loB[s * LSTR + d + 2] = v.z;
        loB[s * LSTR + d + 3] = v.w;
    }
    __syncthreads();

    for (int i = 0; i < 9; i++) {
        const int flat = w + 8 * i;
        const int proj = flat / 24, rem = flat % 24;
        const int mt = rem >> 2, nt = rem & 3;
        const float* wmat = (proj == 0) ? tv_w : (proj == 1) ? tk_w : tq_w;
        const float* bvec = (proj == 0) ? tv_b : (proj == 1) ? tk_b : tq_b;
        const int j = 16 * nt + col;
        f32x4 acc = {0.f, 0.f, 0.f, 0.f};
        #pragma unroll
        for (int kc = 0; kc < 2; kc++) {
            f16x8 a  = frag_from_f32(loB + (16 * mt + col) * LSTR + kc * 32 + quad * 8);
            f16x8 bb = frag_from_f32(wmat + j * HH + kc * 32 + quad * 8);
            acc = __builtin_amdgcn_mfma_f32_16x16x32_f16(a, bb, acc, 0, 0, 0);
        }
        const float bj = bvec[j];
        #pragma unroll
        for (int r = 0; r < 4; r++) {
            const float v = acc[r] + bj;
            const int row = 16 * mt + quad * 4 + r;
            if (proj == 0)      tvT[j * HSTR + row] = (_Float16)v;
            else if (proj == 1) tkS[row * HSTR + j] = (_Float16)v;
            else                qB[row * HSTR + j]  = (_Float16)v;
        }
    }
    __syncthreads();

    if (w < 6) {
        const int mt = w;
        f16x8 aq0 = *(const f16x8*)(qB + (16 * mt + col) * HSTR + quad * 8);
        f16x8 aq1 = *(const f16x8*)(qB + (16 * mt + col) * HSTR + 32 + quad * 8);
        f32x4 sc[6];
        #pragma unroll
        for (int nt = 0; nt < 6; nt++) {
            f32x4 acc = {0.f, 0.f, 0.f, 0.f};
            f16x8 b0 = *(const f16x8*)(tkS + (16 * nt + col) * HSTR + quad * 8);
            f16x8 b1 = *(const f16x8*)(tkS + (16 * nt + col) * HSTR + 32 + quad * 8);
            acc = __builtin_amdgcn_mfma_f32_16x16x32_f16(aq0, b0, acc, 0, 0, 0);
            acc = __builtin_amdgcn_mfma_f32_16x16x32_f16(aq1, b1, acc, 0, 0, 0);
            sc[nt] = acc;
        }
        #pragma unroll
        for (int r = 0; r < 4; r++) {
            float m = sc[0][r];
            #pragma unroll
            for (int nt = 1; nt < 6; nt++) m = fmaxf(m, sc[nt][r]);
            #pragma unroll
            for (int o = 1; o < 16; o <<= 1) m = fmaxf(m, __shfl_xor(m, o));
            float e[6]; float sum = 0.0f;
            #pragma unroll
            for (int nt = 0; nt < 6; nt++) { e[nt] = __expf(sc[nt][r] - m); sum += e[nt]; }
            #pragma unroll
            for (int o = 1; o < 16; o <<= 1) sum += __shfl_xor(sum, o);
            const float inv = 1.0f / sum;
            const int row = 16 * mt + quad * 4 + r;
            #pragma unroll
            for (int nt = 0; nt < 6; nt++)
                qB[row * HSTR + 16 * nt + col] = (_Float16)(e[nt] * inv);
        }
        f16x8 pa0 = *(const f16x8*)(qB + (16 * mt + col) * HSTR + quad * 8);
        f16x8 pa1 = *(const f16x8*)(qB + (16 * mt + col) * HSTR + 32 + quad * 8);
        f16x8 pa2 = *(const f16x8*)(qB + (16 * mt + col) * HSTR + 64 + quad * 8);
        #pragma unroll
        for (int nt = 0; nt < 4; nt++) {
            f32x4 acc = {0.f, 0.f, 0.f, 0.f};
            const _Float16* tvrow = tvT + (16 * nt + col) * HSTR;
            acc = __builtin_amdgcn_mfma_f32_16x16x32_f16(pa0, *(const f16x8*)(tvrow + quad * 8), acc, 0, 0, 0);
            acc = __builtin_amdgcn_mfma_f32_16x16x32_f16(pa1, *(const f16x8*)(tvrow + 32 + quad * 8), acc, 0, 0, 0);
            acc = __builtin_amdgcn_mfma_f32_16x16x32_f16(pa2, *(const f16x8*)(tvrow + 64 + quad * 8), acc, 0, 0, 0);
            #pragma unroll
            for (int r = 0; r < 4; r++)
                loB[(16 * mt + quad * 4 + r) * LSTR + 16 * nt + col] = tanh_f(acc[r]);
        }
    }
    __syncthreads();

    {
        f32x4 xacc[3];
        #pragma unroll
        for (int i = 0; i < 3; i++) {
            const int flat = w + 8 * i;
            const int mt = flat >> 2, nt = flat & 3;
            const int g = 16 * nt + col;
            f32x4 acc = {0.f, 0.f, 0.f, 0.f};
            #pragma unroll
            for (int kc = 0; kc < 2; kc++) {
                f16x8 a  = frag_from_f32(loB + (16 * mt + col) * LSTR + kc * 32 + quad * 8);
                f16x8 bb = frag_from_f32(l2_wih + g * HH + kc * 32 + quad * 8);
                acc = __builtin_amdgcn_mfma_f32_16x16x32_f16(a, bb, acc, 0, 0, 0);
            }
            const float bg = l2_bih[g] + l2_bhh[g];
            #pragma unroll
            for (int r = 0; r < 4; r++) acc[r] += bg;
            xacc[i] = acc;
        }
        __syncthreads();
        #pragma unroll
        for (int i = 0; i < 3; i++) {
            const int flat = w + 8 * i;
            const int mt = flat >> 2, nt = flat & 3;
            const int g = 16 * nt + col;
            #pragma unroll
            for (int r = 0; r < 4; r++)
                loB[(16 * mt + quad * 4 + r) * LSTR + g] = xacc[i][r];
        }
    }
    __syncthreads();

    float* hsb = (float*)tvT;
    if (t < 64) {
        float whr[H2];
        #pragma unroll
        for (int j = 0; j < H2; j++) whr[j] = l2_whh[lane * H2 + j];
        const int myi = lane & 15;
        float h = 0.0f, c = 0.0f;
        for (int s = 0; s < SS; s++) {
            float a = loB[s * LSTR + lane];
            #pragma unroll
            for (int j = 0; j < H2; j++) a += rl(h, j) * whr[j];
            float iv = __shfl(a, myi);
            float fv = __shfl(a, H2 + myi);
            float gv = __shfl(a, 2 * H2 + myi);
            float ov = __shfl(a, 3 * H2 + myi);
            c = sigm(fv) * c + sigm(iv) * tanh_f(gv);
            h = sigm(ov) * tanh_f(c);
            if (lane < H2) hsb[s * 17 + lane] = h;
        }
    }
    __syncthreads();

    if (w < 2) {
        const int srow = w * 64 + lane;
        if (srow < SS) {
            float hreg[H2];
            #pragma unroll
            for (int j = 0; j < H2; j++) hreg[j] = hsb[srow * 17 + j];
            float* op = out + (size_t)b * SS * DD + srow * DD;
            for (int d = 0; d < DD; d++) {
                float a = fc_b[d];
                #pragma unroll
                for (int j = 0; j < H2; j++) a += hreg[j] * fc_w[d * H2 + j];
                op[d] = a;
            }
        }
    }
}

extern "C" void kernel_launch(void* const* d_in, const int* in_sizes, int n_in,
                              void* d_out, int out_size, void* d_ws, size_t ws_size,
                              hipStream_t stream) {
    const float* x     = (const float*)d_in[0];
    const float* fv_w  = (const float*)d_in[1];
    const float* fv_b  = (const float*)d_in[2];
    const float* fk_w  = (const float*)d_in[3];
    const float* fk_b  = (const float*)d_in[4];
    const float* fq_w  = (const float*)d_in[5];
    const float* fq_b  = (const float*)d_in[6];
    const float* l1f_wih = (const float*)d_in[7];
    const float* l1f_whh = (const float*)d_in[8];
    const float* l1f_bih = (const float*)d_in[9];
    const float* l1f_bhh = (const float*)d_in[10];
    const float* l1b_wih = (const float*)d_in[11];
    const float* l1b_whh = (const float*)d_in[12];
    const float* l1b_bih = (const float*)d_in[13];
    const float* l1b_bhh = (const float*)d_in[14];
    const float* tv_w  = (const float*)d_in[15];
    const float* tv_b  = (const float*)d_in[16];
    const float* tk_w  = (const float*)d_in[17];
    const float* tk_b  = (const float*)d_in[18];
    const float* tq_w  = (const float*)d_in[19];
    const float* tq_b  = (const float*)d_in[20];
    const float* l2_wih = (const float*)d_in[21];
    const float* l2_whh = (const float*)d_in[22];
    const float* l2_bih = (const float*)d_in[23];
    const float* l2_bhh = (const float*)d_in[24];
    const float* fc_w  = (const float*)d_in[25];
    const float* fc_b  = (const float*)d_in[26];

    float* fa = (float*)d_ws;                       // B*S*D floats
    float* lo = fa + (size_t)BB * SS * DD;          // B*S*H floats

    k_feat<<<BB, 256, 0, stream>>>(x, fv_w, fv_b, fk_w, fk_b, fq_w, fq_b, fa);
    k_bilstm<<<BB, 512, 0, stream>>>(fa,
        l1f_wih, l1f_whh, l1f_bih, l1f_bhh,
        l1b_wih, l1b_whh, l1b_bih, l1b_bhh, lo);
    k_temporal<<<BB, 512, 0, stream>>>(lo,
        tv_w, tv_b, tk_w, tk_b, tq_w, tq_b,
        l2_wih, l2_whh, l2_bih, l2_bhh, fc_w, fc_b,
        (float*)d_out);
}

// Round 9
// 489.621 us; speedup vs baseline: 2.1395x; 2.1395x over previous
//
#include <hip/hip_runtime.h>
#include <math.h>

#define BB 2048
#define SS 96
#define DD 7
#define HH 64
#define H2 16
#define LSTR 68    // loB row stride (fp32): 68*4=272B -> b128-aligned rows
#define HSTR 104   // f16 tile row stride: 104*2=208B -> b128-aligned rows
#define FASTR 776  // faS row stride (f16): 96*8+8 pad
#define HST2 72    // h dbuf row stride (f16)

typedef _Float16 f16x8 __attribute__((ext_vector_type(8)));
typedef _Float16 f16x4 __attribute__((ext_vector_type(4)));
typedef float f32x4 __attribute__((ext_vector_type(4)));

__device__ __forceinline__ float sigm(float x) { return 1.0f / (1.0f + __expf(-x)); }
__device__ __forceinline__ float tanh_f(float x) { return 1.0f - 2.0f / (__expf(2.0f * x) + 1.0f); }
__device__ __forceinline__ float rl(float v, int l) {
    return __int_as_float(__builtin_amdgcn_readlane(__float_as_int(v), l));
}
// load 8 consecutive fp32 (16B-aligned) -> f16x8 fragment
__device__ __forceinline__ f16x8 frag_from_f32(const float* base) {
    const float4* p = (const float4*)base;
    float4 a = p[0], b = p[1];
    f16x8 r;
    r[0] = (_Float16)a.x; r[1] = (_Float16)a.y; r[2] = (_Float16)a.z; r[3] = (_Float16)a.w;
    r[4] = (_Float16)b.x; r[5] = (_Float16)b.y; r[6] = (_Float16)b.z; r[7] = (_Float16)b.w;
    return r;
}

// ---------------- Kernel 1: feature attention (unchanged) ----------------
__global__ __launch_bounds__(256) void k_feat(
    const float* __restrict__ x,
    const float* __restrict__ fv_w, const float* __restrict__ fv_b,
    const float* __restrict__ fk_w, const float* __restrict__ fk_b,
    const float* __restrict__ fq_w, const float* __restrict__ fq_b,
    float* __restrict__ fa_out)
{
    __shared__ float xs[SS * DD], vs[SS * DD], ks[SS * DD], qs[SS * DD];
    __shared__ float att[DD * DD];
    __shared__ float wv[DD * DD], wk[DD * DD], wq[DD * DD];
    __shared__ float bv[DD], bk[DD], bq[DD];
    const int b = blockIdx.x, t = threadIdx.x;
    const float* xb = x + (size_t)b * SS * DD;

    for (int idx = t; idx < SS * DD; idx += 256) xs[idx] = xb[idx];
    if (t < DD * DD) { wv[t] = fv_w[t]; wk[t] = fk_w[t]; wq[t] = fq_w[t]; }
    if (t < DD)      { bv[t] = fv_b[t]; bk[t] = fk_b[t]; bq[t] = fq_b[t]; }
    __syncthreads();

    for (int idx = t; idx < SS * DD; idx += 256) {
        int s = idx / DD, j = idx % DD;
        float a = bv[j];
        #pragma unroll
        for (int i = 0; i < DD; i++) a += xs[s * DD + i] * wv[j * DD + i];
        vs[idx] = a;
    }
    __syncthreads();
    for (int idx = t; idx < SS * DD; idx += 256) {
        int s = idx / DD, j = idx % DD;
        float a = bk[j];
        #pragma unroll
        for (int i = 0; i < DD; i++) a += (xs[s * DD + i] + vs[s * DD + i]) * wk[j * DD + i];
        ks[idx] = a;
    }
    __syncthreads();
    for (int idx = t; idx < SS * DD; idx += 256) {
        int s = idx / DD, j = idx % DD;
        float a = bq[j];
        #pragma unroll
        for (int i = 0; i < DD; i++) a += (xs[s * DD + i] + ks[s * DD + i]) * wq[j * DD + i];
        qs[idx] = a;
    }
    __syncthreads();
    if (t < DD * DD) {
        int i = t / DD, j = t % DD;
        float a = 0.0f;
        for (int s = 0; s < SS; s++) a += qs[s * DD + i] * ks[s * DD + j];
        att[t] = a;
    }
    __syncthreads();
    if (t < DD) {
        float m = -1e30f;
        #pragma unroll
        for (int j = 0; j < DD; j++) m = fmaxf(m, att[t * DD + j]);
        float e[DD]; float sum = 0.0f;
        #pragma unroll
        for (int j = 0; j < DD; j++) { e[j] = __expf(att[t * DD + j] - m); sum += e[j]; }
        float inv = 1.0f / sum;
        #pragma unroll
        for (int j = 0; j < DD; j++) att[t * DD + j] = e[j] * inv;
    }
    __syncthreads();
    for (int idx = t; idx < SS * DD; idx += 256) {
        int s = idx / DD, j = idx % DD;
        float a = xs[idx];
        #pragma unroll
        for (int i = 0; i < DD; i++) a += vs[s * DD + i] * att[i * DD + j];
        fa_out[(size_t)b * SS * DD + idx] = tanh_f(a);
    }
}

// ---------------- Kernel 2: MFMA-batched bidirectional LSTM ----------------
// block = 8 batch elements x 1 direction, 256 thr (4 waves). 512 blocks.
// Per step: G[256,16] = Wih_pad @ [fa_s;1] + Whh @ h  via 12 MFMA/wave.
// Wave w owns units 16w..16w+15 (m-tiles w, w+4, w+8, w+12) -> i,f,g,o of a
// lane's 4 units land in that lane's C-frags; c stays in VGPRs; weights are
// 12 resident A-fragments (vector values -> regalloc keeps them).
__global__ __launch_bounds__(256) void k_bilstm(
    const float* __restrict__ fa,
    const float* __restrict__ wih_f, const float* __restrict__ whh_f,
    const float* __restrict__ bih_f, const float* __restrict__ bhh_f,
    const float* __restrict__ wih_b, const float* __restrict__ whh_b,
    const float* __restrict__ bih_b, const float* __restrict__ bhh_b,
    _Float16* __restrict__ hf, _Float16* __restrict__ hb)
{
    __shared__ _Float16 faS[16 * FASTR];   // [batch n][s*8 + i], i=7 holds 1.0
    __shared__ _Float16 hS[2][16 * HST2];  // h dbuf: [n][unit]

    const int bx = blockIdx.x;
    const int bg = bx >> 1, dir = bx & 1;
    const int t = threadIdx.x, lane = t & 63, w = t >> 6;
    const int col = lane & 15, quad = lane >> 4;

    const float* wih = dir ? wih_b : wih_f;
    const float* whh = dir ? whh_b : whh_f;
    const float* bih = dir ? bih_b : bih_f;
    const float* bhh = dir ? bhh_b : bhh_f;
    _Float16* hout = dir ? hb : hf;

    // zero faS (incl. dummy rows 8-15) and both h buffers
    for (int i = t; i < 16 * FASTR / 2; i += 256) ((unsigned int*)faS)[i] = 0u;
    for (int i = t; i < 2 * 16 * HST2 / 2; i += 256) ((unsigned int*)hS)[i] = 0u;

    // resident weight A-fragments
    f16x8 wh[4][2];
    f16x8 wi[4];
    #pragma unroll
    for (int gt = 0; gt < 4; gt++) {
        const int row = 16 * (w + 4 * gt) + col;
        wh[gt][0] = frag_from_f32(whh + row * HH + quad * 8);
        wh[gt][1] = frag_from_f32(whh + row * HH + 32 + quad * 8);
        f16x8 v;
        #pragma unroll
        for (int j = 0; j < 8; j++) v[j] = (_Float16)0.0f;
        if (quad == 0) {
            #pragma unroll
            for (int j = 0; j < DD; j++) v[j] = (_Float16)wih[row * DD + j];
            v[7] = (_Float16)(bih[row] + bhh[row]);
        }
        wi[gt] = v;
    }
    __syncthreads();   // zeroing done

    // fill faS rows 0..7 with fa (f16) + ones column
    const float* fab = fa + (size_t)(bg * 8) * SS * DD;
    for (int idx = t; idx < 8 * SS * DD; idx += 256) {
        int n = idx / (SS * DD), r = idx % (SS * DD);
        int s = r / DD, i = r % DD;
        faS[n * FASTR + s * 8 + i] = (_Float16)fab[idx];
    }
    for (int idx = t; idx < 8 * SS; idx += 256) {
        int n = idx / SS, s = idx % SS;
        faS[n * FASTR + s * 8 + 7] = (_Float16)1.0f;
    }
    __syncthreads();

    float c0 = 0.f, c1 = 0.f, c2 = 0.f, c3 = 0.f;

    for (int step = 0; step < SS; step++) {
        const int s = dir ? (SS - 1 - step) : step;
        const int p = step & 1;

        f16x8 h0 = *(const f16x8*)(&hS[p][col * HST2 + quad * 8]);
        f16x8 h1 = *(const f16x8*)(&hS[p][col * HST2 + 32 + quad * 8]);
        f16x8 faf;
        #pragma unroll
        for (int j = 0; j < 8; j++) faf[j] = (_Float16)0.0f;
        if (quad == 0) faf = *(const f16x8*)(&faS[col * FASTR + s * 8]);

        f32x4 g[4];
        #pragma unroll
        for (int gt = 0; gt < 4; gt++) {
            f32x4 acc = {0.f, 0.f, 0.f, 0.f};
            acc = __builtin_amdgcn_mfma_f32_16x16x32_f16(wi[gt], faf, acc, 0, 0, 0);
            acc = __builtin_amdgcn_mfma_f32_16x16x32_f16(wh[gt][0], h0, acc, 0, 0, 0);
            acc = __builtin_amdgcn_mfma_f32_16x16x32_f16(wh[gt][1], h1, acc, 0, 0, 0);
            g[gt] = acc;
        }
        // lane holds i,f,g,o for units 16w+quad*4+{0..3}, batch col
        f16x4 hq;
        {
            float iv, fv, gv, ov, hv;
            iv = sigm(g[0][0]); fv = sigm(g[1][0]); gv = tanh_f(g[2][0]); ov = sigm(g[3][0]);
            c0 = fv * c0 + iv * gv; hv = ov * tanh_f(c0); hq[0] = (_Float16)hv;
            iv = sigm(g[0][1]); fv = sigm(g[1][1]); gv = tanh_f(g[2][1]); ov = sigm(g[3][1]);
            c1 = fv * c1 + iv * gv; hv = ov * tanh_f(c1); hq[1] = (_Float16)hv;
            iv = sigm(g[0][2]); fv = sigm(g[1][2]); gv = tanh_f(g[2][2]); ov = sigm(g[3][2]);
            c2 = fv * c2 + iv * gv; hv = ov * tanh_f(c2); hq[2] = (_Float16)hv;
            iv = sigm(g[0][3]); fv = sigm(g[1][3]); gv = tanh_f(g[2][3]); ov = sigm(g[3][3]);
            c3 = fv * c3 + iv * gv; hv = ov * tanh_f(c3); hq[3] = (_Float16)hv;
        }
        *(f16x4*)(&hS[1 - p][col * HST2 + 16 * w + quad * 4]) = hq;
        __syncthreads();

        // coalesced global store of this step's h (valid batches 0..7)
        #pragma unroll
        for (int it = 0; it < 2; it++) {
            const int idx = t + 256 * it;        // 0..511 = 8 batches x 64 units
            const int n = idx >> 6, u = idx & 63;
            hout[((size_t)(bg * 8 + n)) * SS * HH + s * HH + u] = hS[1 - p][n * HST2 + u];
        }
    }
}

// ---------------- Kernel 3: temporal attention via MFMA f16 + LSTM2 + fc ----------------
__global__ __launch_bounds__(512, 2) void k_temporal(
    const _Float16* __restrict__ hf, const _Float16* __restrict__ hb,
    const float* __restrict__ tv_w, const float* __restrict__ tv_b,
    const float* __restrict__ tk_w, const float* __restrict__ tk_b,
    const float* __restrict__ tq_w, const float* __restrict__ tq_b,
    const float* __restrict__ l2_wih, const float* __restrict__ l2_whh,
    const float* __restrict__ l2_bih, const float* __restrict__ l2_bhh,
    const float* __restrict__ fc_w, const float* __restrict__ fc_b,
    float* __restrict__ out)
{
    __shared__ float loB[SS * LSTR];        // lo -> 'to' -> xg2
    __shared__ _Float16 qB[SS * HSTR];      // q[s][f]; later p[s][P]
    __shared__ _Float16 tkS[SS * HSTR];     // tk[s][f]
    __shared__ _Float16 tvT[HH * HSTR];     // tv^T[d][P]; later hsb fp32[96*17]

    const int b = blockIdx.x, t = threadIdx.x;
    const int lane = t & 63, w = t >> 6;
    const int col = lane & 15, quad = lane >> 4;

    // lo = 0.5*(hf+hb), f16 in -> fp32 tile
    const _Float16* hfp = hf + (size_t)b * SS * HH;
    const _Float16* hbp = hb + (size_t)b * SS * HH;
    for (int g8 = t; g8 < 768; g8 += 512) {
        f16x8 va = *(const f16x8*)(hfp + g8 * 8);
        f16x8 vb = *(const f16x8*)(hbp + g8 * 8);
        int s = g8 >> 3, d = (g8 & 7) * 8;
        #pragma unroll
        for (int j = 0; j < 8; j++)
            loB[s * LSTR + d + j] = 0.5f * ((float)va[j] + (float)vb[j]);
    }
    __syncthreads();

    for (int i = 0; i < 9; i++) {
        const int flat = w + 8 * i;
        const int proj = flat / 24, rem = flat % 24;
        const int mt = rem >> 2, nt = rem & 3;
        const float* wmat = (proj == 0) ? tv_w : (proj == 1) ? tk_w : tq_w;
        const float* bvec = (proj == 0) ? tv_b : (proj == 1) ? tk_b : tq_b;
        const int j = 16 * nt + col;
        f32x4 acc = {0.f, 0.f, 0.f, 0.f};
        #pragma unroll
        for (int kc = 0; kc < 2; kc++) {
            f16x8 a  = frag_from_f32(loB + (16 * mt + col) * LSTR + kc * 32 + quad * 8);
            f16x8 bb = frag_from_f32(wmat + j * HH + kc * 32 + quad * 8);
            acc = __builtin_amdgcn_mfma_f32_16x16x32_f16(a, bb, acc, 0, 0, 0);
        }
        const float bj = bvec[j];
        #pragma unroll
        for (int r = 0; r < 4; r++) {
            const float v = acc[r] + bj;
            const int row = 16 * mt + quad * 4 + r;
            if (proj == 0)      tvT[j * HSTR + row] = (_Float16)v;
            else if (proj == 1) tkS[row * HSTR + j] = (_Float16)v;
            else                qB[row * HSTR + j]  = (_Float16)v;
        }
    }
    __syncthreads();

    if (w < 6) {
        const int mt = w;
        f16x8 aq0 = *(const f16x8*)(qB + (16 * mt + col) * HSTR + quad * 8);
        f16x8 aq1 = *(const f16x8*)(qB + (16 * mt + col) * HSTR + 32 + quad * 8);
        f32x4 sc[6];
        #pragma unroll
        for (int nt = 0; nt < 6; nt++) {
            f32x4 acc = {0.f, 0.f, 0.f, 0.f};
            f16x8 b0 = *(const f16x8*)(tkS + (16 * nt + col) * HSTR + quad * 8);
            f16x8 b1 = *(const f16x8*)(tkS + (16 * nt + col) * HSTR + 32 + quad * 8);
            acc = __builtin_amdgcn_mfma_f32_16x16x32_f16(aq0, b0, acc, 0, 0, 0);
            acc = __builtin_amdgcn_mfma_f32_16x16x32_f16(aq1, b1, acc, 0, 0, 0);
            sc[nt] = acc;
        }
        #pragma unroll
        for (int r = 0; r < 4; r++) {
            float m = sc[0][r];
            #pragma unroll
            for (int nt = 1; nt < 6; nt++) m = fmaxf(m, sc[nt][r]);
            #pragma unroll
            for (int o = 1; o < 16; o <<= 1) m = fmaxf(m, __shfl_xor(m, o));
            float e[6]; float sum = 0.0f;
            #pragma unroll
            for (int nt = 0; nt < 6; nt++) { e[nt] = __expf(sc[nt][r] - m); sum += e[nt]; }
            #pragma unroll
            for (int o = 1; o < 16; o <<= 1) sum += __shfl_xor(sum, o);
            const float inv = 1.0f / sum;
            const int row = 16 * mt + quad * 4 + r;
            #pragma unroll
            for (int nt = 0; nt < 6; nt++)
                qB[row * HSTR + 16 * nt + col] = (_Float16)(e[nt] * inv);
        }
        f16x8 pa0 = *(const f16x8*)(qB + (16 * mt + col) * HSTR + quad * 8);
        f16x8 pa1 = *(const f16x8*)(qB + (16 * mt + col) * HSTR + 32 + quad * 8);
        f16x8 pa2 = *(const f16x8*)(qB + (16 * mt + col) * HSTR + 64 + quad * 8);
        #pragma unroll
        for (int nt = 0; nt < 4; nt++) {
            f32x4 acc = {0.f, 0.f, 0.f, 0.f};
            const _Float16* tvrow = tvT + (16 * nt + col) * HSTR;
            acc = __builtin_amdgcn_mfma_f32_16x16x32_f16(pa0, *(const f16x8*)(tvrow + quad * 8), acc, 0, 0, 0);
            acc = __builtin_amdgcn_mfma_f32_16x16x32_f16(pa1, *(const f16x8*)(tvrow + 32 + quad * 8), acc, 0, 0, 0);
            acc = __builtin_amdgcn_mfma_f32_16x16x32_f16(pa2, *(const f16x8*)(tvrow + 64 + quad * 8), acc, 0, 0, 0);
            #pragma unroll
            for (int r = 0; r < 4; r++)
                loB[(16 * mt + quad * 4 + r) * LSTR + 16 * nt + col] = tanh_f(acc[r]);
        }
    }
    __syncthreads();

    {
        f32x4 xacc[3];
        #pragma unroll
        for (int i = 0; i < 3; i++) {
            const int flat = w + 8 * i;
            const int mt = flat >> 2, nt = flat & 3;
            const int g = 16 * nt + col;
            f32x4 acc = {0.f, 0.f, 0.f, 0.f};
            #pragma unroll
            for (int kc = 0; kc < 2; kc++) {
                f16x8 a  = frag_from_f32(loB + (16 * mt + col) * LSTR + kc * 32 + quad * 8);
                f16x8 bb = frag_from_f32(l2_wih + g * HH + kc * 32 + quad * 8);
                acc = __builtin_amdgcn_mfma_f32_16x16x32_f16(a, bb, acc, 0, 0, 0);
            }
            const float bg = l2_bih[g] + l2_bhh[g];
            #pragma unroll
            for (int r = 0; r < 4; r++) acc[r] += bg;
            xacc[i] = acc;
        }
        __syncthreads();
        #pragma unroll
        for (int i = 0; i < 3; i++) {
            const int flat = w + 8 * i;
            const int mt = flat >> 2, nt = flat & 3;
            const int g = 16 * nt + col;
            #pragma unroll
            for (int r = 0; r < 4; r++)
                loB[(16 * mt + quad * 4 + r) * LSTR + g] = xacc[i][r];
        }
    }
    __syncthreads();

    float* hsb = (float*)tvT;
    if (t < 64) {
        float whr[H2];
        #pragma unroll
        for (int j = 0; j < H2; j++) whr[j] = l2_whh[lane * H2 + j];
        const int myi = lane & 15;
        float h = 0.0f, c = 0.0f;
        for (int s = 0; s < SS; s++) {
            float a = loB[s * LSTR + lane];
            #pragma unroll
            for (int j = 0; j < H2; j++) a += rl(h, j) * whr[j];
            float iv = __shfl(a, myi);
            float fv = __shfl(a, H2 + myi);
            float gv = __shfl(a, 2 * H2 + myi);
            float ov = __shfl(a, 3 * H2 + myi);
            c = sigm(fv) * c + sigm(iv) * tanh_f(gv);
            h = sigm(ov) * tanh_f(c);
            if (lane < H2) hsb[s * 17 + lane] = h;
        }
    }
    __syncthreads();

    if (w < 2) {
        const int srow = w * 64 + lane;
        if (srow < SS) {
            float hreg[H2];
            #pragma unroll
            for (int j = 0; j < H2; j++) hreg[j] = hsb[srow * 17 + j];
            float* op = out + (size_t)b * SS * DD + srow * DD;
            for (int d = 0; d < DD; d++) {
                float a = fc_b[d];
                #pragma unroll
                for (int j = 0; j < H2; j++) a += hreg[j] * fc_w[d * H2 + j];
                op[d] = a;
            }
        }
    }
}

extern "C" void kernel_launch(void* const* d_in, const int* in_sizes, int n_in,
                              void* d_out, int out_size, void* d_ws, size_t ws_size,
                              hipStream_t stream) {
    const float* x     = (const float*)d_in[0];
    const float* fv_w  = (const float*)d_in[1];
    const float* fv_b  = (const float*)d_in[2];
    const float* fk_w  = (const float*)d_in[3];
    const float* fk_b  = (const float*)d_in[4];
    const float* fq_w  = (const float*)d_in[5];
    const float* fq_b  = (const float*)d_in[6];
    const float* l1f_wih = (const float*)d_in[7];
    const float* l1f_whh = (const float*)d_in[8];
    const float* l1f_bih = (const float*)d_in[9];
    const float* l1f_bhh = (const float*)d_in[10];
    const float* l1b_wih = (const float*)d_in[11];
    const float* l1b_whh = (const float*)d_in[12];
    const float* l1b_bih = (const float*)d_in[13];
    const float* l1b_bhh = (const float*)d_in[14];
    const float* tv_w  = (const float*)d_in[15];
    const float* tv_b  = (const float*)d_in[16];
    const float* tk_w  = (const float*)d_in[17];
    const float* tk_b  = (const float*)d_in[18];
    const float* tq_w  = (const float*)d_in[19];
    const float* tq_b  = (const float*)d_in[20];
    const float* l2_wih = (const float*)d_in[21];
    const float* l2_whh = (const float*)d_in[22];
    const float* l2_bih = (const float*)d_in[23];
    const float* l2_bhh = (const float*)d_in[24];
    const float* fc_w  = (const float*)d_in[25];
    const float* fc_b  = (const float*)d_in[26];

    float* fa = (float*)d_ws;                              // B*S*D fp32
    _Float16* hf = (_Float16*)(fa + (size_t)BB * SS * DD); // B*S*H f16
    _Float16* hb = hf + (size_t)BB * SS * HH;              // B*S*H f16

    k_feat<<<BB, 256, 0, stream>>>(x, fv_w, fv_b, fk_w, fk_b, fq_w, fq_b, fa);
    k_bilstm<<<512, 256, 0, stream>>>(fa,
        l1f_wih, l1f_whh, l1f_bih, l1f_bhh,
        l1b_wih, l1b_whh, l1b_bih, l1b_bhh, hf, hb);
    k_temporal<<<BB, 512, 0, stream>>>(hf, hb,
        tv_w, tv_b, tk_w, tk_b, tq_w, tq_b,
        l2_wih, l2_whh, l2_bih, l2_bhh, fc_w, fc_b,
        (float*)d_out);
}

// Round 10
// 461.668 us; speedup vs baseline: 2.2691x; 1.0605x over previous
//
#include <hip/hip_runtime.h>
#include <math.h>

#define BB 2048
#define SS 96
#define DD 7
#define HH 64
#define H2 16
#define FASTR 776  // k_bilstm faS row stride (f16)
#define HST2 72    // k_bilstm h dbuf row stride (f16)
#define LOST2 88   // k_attn loB f16 stride (44 dw % 32 = 12 -> 2-way, free)
#define KST 120    // k_attn qB/tkS/tvT f16 stride (60 dw % 32 = 28 -> 2-way)
#define XGST 72    // k_lstm2 xgS staging stride (f16) per (s,n) row
#define HTST 40    // k_lstm2 hT stride (f16), cols 16..39 stay zero (K-pad)

typedef _Float16 f16x8 __attribute__((ext_vector_type(8)));
typedef _Float16 f16x4 __attribute__((ext_vector_type(4)));
typedef float f32x4 __attribute__((ext_vector_type(4)));

__device__ __forceinline__ float sigm(float x) { return 1.0f / (1.0f + __expf(-x)); }
__device__ __forceinline__ float tanh_f(float x) { return 1.0f - 2.0f / (__expf(2.0f * x) + 1.0f); }
__device__ __forceinline__ float rl(float v, int l) {
    return __int_as_float(__builtin_amdgcn_readlane(__float_as_int(v), l));
}
// load 8 consecutive fp32 (16B-aligned) -> f16x8 fragment
__device__ __forceinline__ f16x8 frag_from_f32(const float* base) {
    const float4* p = (const float4*)base;
    float4 a = p[0], b = p[1];
    f16x8 r;
    r[0] = (_Float16)a.x; r[1] = (_Float16)a.y; r[2] = (_Float16)a.z; r[3] = (_Float16)a.w;
    r[4] = (_Float16)b.x; r[5] = (_Float16)b.y; r[6] = (_Float16)b.z; r[7] = (_Float16)b.w;
    return r;
}

// ---------------- Kernel 1: feature attention (unchanged) ----------------
__global__ __launch_bounds__(256) void k_feat(
    const float* __restrict__ x,
    const float* __restrict__ fv_w, const float* __restrict__ fv_b,
    const float* __restrict__ fk_w, const float* __restrict__ fk_b,
    const float* __restrict__ fq_w, const float* __restrict__ fq_b,
    float* __restrict__ fa_out)
{
    __shared__ float xs[SS * DD], vs[SS * DD], ks[SS * DD], qs[SS * DD];
    __shared__ float att[DD * DD];
    __shared__ float wv[DD * DD], wk[DD * DD], wq[DD * DD];
    __shared__ float bv[DD], bk[DD], bq[DD];
    const int b = blockIdx.x, t = threadIdx.x;
    const float* xb = x + (size_t)b * SS * DD;

    for (int idx = t; idx < SS * DD; idx += 256) xs[idx] = xb[idx];
    if (t < DD * DD) { wv[t] = fv_w[t]; wk[t] = fk_w[t]; wq[t] = fq_w[t]; }
    if (t < DD)      { bv[t] = fv_b[t]; bk[t] = fk_b[t]; bq[t] = fq_b[t]; }
    __syncthreads();

    for (int idx = t; idx < SS * DD; idx += 256) {
        int s = idx / DD, j = idx % DD;
        float a = bv[j];
        #pragma unroll
        for (int i = 0; i < DD; i++) a += xs[s * DD + i] * wv[j * DD + i];
        vs[idx] = a;
    }
    __syncthreads();
    for (int idx = t; idx < SS * DD; idx += 256) {
        int s = idx / DD, j = idx % DD;
        float a = bk[j];
        #pragma unroll
        for (int i = 0; i < DD; i++) a += (xs[s * DD + i] + vs[s * DD + i]) * wk[j * DD + i];
        ks[idx] = a;
    }
    __syncthreads();
    for (int idx = t; idx < SS * DD; idx += 256) {
        int s = idx / DD, j = idx % DD;
        float a = bq[j];
        #pragma unroll
        for (int i = 0; i < DD; i++) a += (xs[s * DD + i] + ks[s * DD + i]) * wq[j * DD + i];
        qs[idx] = a;
    }
    __syncthreads();
    if (t < DD * DD) {
        int i = t / DD, j = t % DD;
        float a = 0.0f;
        for (int s = 0; s < SS; s++) a += qs[s * DD + i] * ks[s * DD + j];
        att[t] = a;
    }
    __syncthreads();
    if (t < DD) {
        float m = -1e30f;
        #pragma unroll
        for (int j = 0; j < DD; j++) m = fmaxf(m, att[t * DD + j]);
        float e[DD]; float sum = 0.0f;
        #pragma unroll
        for (int j = 0; j < DD; j++) { e[j] = __expf(att[t * DD + j] - m); sum += e[j]; }
        float inv = 1.0f / sum;
        #pragma unroll
        for (int j = 0; j < DD; j++) att[t * DD + j] = e[j] * inv;
    }
    __syncthreads();
    for (int idx = t; idx < SS * DD; idx += 256) {
        int s = idx / DD, j = idx % DD;
        float a = xs[idx];
        #pragma unroll
        for (int i = 0; i < DD; i++) a += vs[s * DD + i] * att[i * DD + j];
        fa_out[(size_t)b * SS * DD + idx] = tanh_f(a);
    }
}

// ---------------- Kernel 2: MFMA-batched bidirectional LSTM (unchanged) ----------------
__global__ __launch_bounds__(256) void k_bilstm(
    const float* __restrict__ fa,
    const float* __restrict__ wih_f, const float* __restrict__ whh_f,
    const float* __restrict__ bih_f, const float* __restrict__ bhh_f,
    const float* __restrict__ wih_b, const float* __restrict__ whh_b,
    const float* __restrict__ bih_b, const float* __restrict__ bhh_b,
    _Float16* __restrict__ hf, _Float16* __restrict__ hb)
{
    __shared__ _Float16 faS[16 * FASTR];
    __shared__ _Float16 hS[2][16 * HST2];

    const int bx = blockIdx.x;
    const int bg = bx >> 1, dir = bx & 1;
    const int t = threadIdx.x, lane = t & 63, w = t >> 6;
    const int col = lane & 15, quad = lane >> 4;

    const float* wih = dir ? wih_b : wih_f;
    const float* whh = dir ? whh_b : whh_f;
    const float* bih = dir ? bih_b : bih_f;
    const float* bhh = dir ? bhh_b : bhh_f;
    _Float16* hout = dir ? hb : hf;

    for (int i = t; i < 16 * FASTR / 2; i += 256) ((unsigned int*)faS)[i] = 0u;
    for (int i = t; i < 2 * 16 * HST2 / 2; i += 256) ((unsigned int*)hS)[i] = 0u;

    f16x8 wh[4][2];
    f16x8 wi[4];
    #pragma unroll
    for (int gt = 0; gt < 4; gt++) {
        const int row = 16 * (w + 4 * gt) + col;
        wh[gt][0] = frag_from_f32(whh + row * HH + quad * 8);
        wh[gt][1] = frag_from_f32(whh + row * HH + 32 + quad * 8);
        f16x8 v;
        #pragma unroll
        for (int j = 0; j < 8; j++) v[j] = (_Float16)0.0f;
        if (quad == 0) {
            #pragma unroll
            for (int j = 0; j < DD; j++) v[j] = (_Float16)wih[row * DD + j];
            v[7] = (_Float16)(bih[row] + bhh[row]);
        }
        wi[gt] = v;
    }
    __syncthreads();

    const float* fab = fa + (size_t)(bg * 8) * SS * DD;
    for (int idx = t; idx < 8 * SS * DD; idx += 256) {
        int n = idx / (SS * DD), r = idx % (SS * DD);
        int s = r / DD, i = r % DD;
        faS[n * FASTR + s * 8 + i] = (_Float16)fab[idx];
    }
    for (int idx = t; idx < 8 * SS; idx += 256) {
        int n = idx / SS, s = idx % SS;
        faS[n * FASTR + s * 8 + 7] = (_Float16)1.0f;
    }
    __syncthreads();

    float c0 = 0.f, c1 = 0.f, c2 = 0.f, c3 = 0.f;

    for (int step = 0; step < SS; step++) {
        const int s = dir ? (SS - 1 - step) : step;
        const int p = step & 1;

        f16x8 h0 = *(const f16x8*)(&hS[p][col * HST2 + quad * 8]);
        f16x8 h1 = *(const f16x8*)(&hS[p][col * HST2 + 32 + quad * 8]);
        f16x8 faf;
        #pragma unroll
        for (int j = 0; j < 8; j++) faf[j] = (_Float16)0.0f;
        if (quad == 0) faf = *(const f16x8*)(&faS[col * FASTR + s * 8]);

        f32x4 g[4];
        #pragma unroll
        for (int gt = 0; gt < 4; gt++) {
            f32x4 acc = {0.f, 0.f, 0.f, 0.f};
            acc = __builtin_amdgcn_mfma_f32_16x16x32_f16(wi[gt], faf, acc, 0, 0, 0);
            acc = __builtin_amdgcn_mfma_f32_16x16x32_f16(wh[gt][0], h0, acc, 0, 0, 0);
            acc = __builtin_amdgcn_mfma_f32_16x16x32_f16(wh[gt][1], h1, acc, 0, 0, 0);
            g[gt] = acc;
        }
        f16x4 hq;
        {
            float iv, fv, gv, ov, hv;
            iv = sigm(g[0][0]); fv = sigm(g[1][0]); gv = tanh_f(g[2][0]); ov = sigm(g[3][0]);
            c0 = fv * c0 + iv * gv; hv = ov * tanh_f(c0); hq[0] = (_Float16)hv;
            iv = sigm(g[0][1]); fv = sigm(g[1][1]); gv = tanh_f(g[2][1]); ov = sigm(g[3][1]);
            c1 = fv * c1 + iv * gv; hv = ov * tanh_f(c1); hq[1] = (_Float16)hv;
            iv = sigm(g[0][2]); fv = sigm(g[1][2]); gv = tanh_f(g[2][2]); ov = sigm(g[3][2]);
            c2 = fv * c2 + iv * gv; hv = ov * tanh_f(c2); hq[2] = (_Float16)hv;
            iv = sigm(g[0][3]); fv = sigm(g[1][3]); gv = tanh_f(g[2][3]); ov = sigm(g[3][3]);
            c3 = fv * c3 + iv * gv; hv = ov * tanh_f(c3); hq[3] = (_Float16)hv;
        }
        *(f16x4*)(&hS[1 - p][col * HST2 + 16 * w + quad * 4]) = hq;
        __syncthreads();

        #pragma unroll
        for (int it = 0; it < 2; it++) {
            const int idx = t + 256 * it;
            const int n = idx >> 6, u = idx & 63;
            hout[((size_t)(bg * 8 + n)) * SS * HH + s * HH + u] = hS[1 - p][n * HST2 + u];
        }
    }
}

// ---------------- Kernel 3: temporal attention (MFMA f16, conflict-free strides) ----------------
// Writes xg2 (f16, [b][s][64]) to global — overlaid on hf region (block-local WAR, safe).
__global__ __launch_bounds__(512, 2) void k_attn(
    const _Float16* __restrict__ hf, const _Float16* __restrict__ hb,
    const float* __restrict__ tv_w, const float* __restrict__ tv_b,
    const float* __restrict__ tk_w, const float* __restrict__ tk_b,
    const float* __restrict__ tq_w, const float* __restrict__ tq_b,
    const float* __restrict__ l2_wih,
    const float* __restrict__ l2_bih, const float* __restrict__ l2_bhh,
    _Float16* __restrict__ xg2)
{
    __shared__ _Float16 loB[SS * LOST2];   // lo -> 'to'
    __shared__ _Float16 qB[SS * KST];      // q[s][f] -> p[s][P]
    __shared__ _Float16 tkS[SS * KST];     // tk[s][f]
    __shared__ _Float16 tvT[HH * KST];     // tv^T[d][P]

    const int b = blockIdx.x, t = threadIdx.x;
    const int lane = t & 63, w = t >> 6;
    const int col = lane & 15, quad = lane >> 4;

    // lo = 0.5*(hf+hb) -> f16 tile
    const _Float16* hfp = hf + (size_t)b * SS * HH;
    const _Float16* hbp = hb + (size_t)b * SS * HH;
    for (int g8 = t; g8 < 768; g8 += 512) {
        f16x8 va = *(const f16x8*)(hfp + g8 * 8);
        f16x8 vb = *(const f16x8*)(hbp + g8 * 8);
        int s = g8 >> 3, d = (g8 & 7) * 8;
        f16x8 r;
        #pragma unroll
        for (int j = 0; j < 8; j++) r[j] = (_Float16)(0.5f * ((float)va[j] + (float)vb[j]));
        *(f16x8*)(&loB[s * LOST2 + d]) = r;
    }
    __syncthreads();

    // projections tv/tk/tq: 72 tile-jobs, 9 per wave; A-frags direct f16 b128
    for (int i = 0; i < 9; i++) {
        const int flat = w + 8 * i;
        const int proj = flat / 24, rem = flat % 24;
        const int mt = rem >> 2, nt = rem & 3;
        const float* wmat = (proj == 0) ? tv_w : (proj == 1) ? tk_w : tq_w;
        const float* bvec = (proj == 0) ? tv_b : (proj == 1) ? tk_b : tq_b;
        const int j = 16 * nt + col;
        f32x4 acc = {0.f, 0.f, 0.f, 0.f};
        #pragma unroll
        for (int kc = 0; kc < 2; kc++) {
            f16x8 a  = *(const f16x8*)(&loB[(16 * mt + col) * LOST2 + kc * 32 + quad * 8]);
            f16x8 bb = frag_from_f32(wmat + j * HH + kc * 32 + quad * 8);
            acc = __builtin_amdgcn_mfma_f32_16x16x32_f16(a, bb, acc, 0, 0, 0);
        }
        const float bj = bvec[j];
        #pragma unroll
        for (int r = 0; r < 4; r++) {
            const float v = acc[r] + bj;
            const int row = 16 * mt + quad * 4 + r;
            if (proj == 0)      tvT[j * KST + row] = (_Float16)v;
            else if (proj == 1) tkS[row * KST + j] = (_Float16)v;
            else                qB[row * KST + j]  = (_Float16)v;
        }
    }
    __syncthreads();

    // scores -> softmax -> P -> PV -> 'to' (waves 0..5, row-tile mt=w)
    if (w < 6) {
        const int mt = w;
        f16x8 aq0 = *(const f16x8*)(qB + (16 * mt + col) * KST + quad * 8);
        f16x8 aq1 = *(const f16x8*)(qB + (16 * mt + col) * KST + 32 + quad * 8);
        f32x4 sc[6];
        #pragma unroll
        for (int nt = 0; nt < 6; nt++) {
            f32x4 acc = {0.f, 0.f, 0.f, 0.f};
            f16x8 b0 = *(const f16x8*)(tkS + (16 * nt + col) * KST + quad * 8);
            f16x8 b1 = *(const f16x8*)(tkS + (16 * nt + col) * KST + 32 + quad * 8);
            acc = __builtin_amdgcn_mfma_f32_16x16x32_f16(aq0, b0, acc, 0, 0, 0);
            acc = __builtin_amdgcn_mfma_f32_16x16x32_f16(aq1, b1, acc, 0, 0, 0);
            sc[nt] = acc;
        }
        #pragma unroll
        for (int r = 0; r < 4; r++) {
            float m = sc[0][r];
            #pragma unroll
            for (int nt = 1; nt < 6; nt++) m = fmaxf(m, sc[nt][r]);
            #pragma unroll
            for (int o = 1; o < 16; o <<= 1) m = fmaxf(m, __shfl_xor(m, o));
            float e[6]; float sum = 0.0f;
            #pragma unroll
            for (int nt = 0; nt < 6; nt++) { e[nt] = __expf(sc[nt][r] - m); sum += e[nt]; }
            #pragma unroll
            for (int o = 1; o < 16; o <<= 1) sum += __shfl_xor(sum, o);
            const float inv = 1.0f / sum;
            const int row = 16 * mt + quad * 4 + r;
            #pragma unroll
            for (int nt = 0; nt < 6; nt++)
                qB[row * KST + 16 * nt + col] = (_Float16)(e[nt] * inv);
        }
        f16x8 pa0 = *(const f16x8*)(qB + (16 * mt + col) * KST + quad * 8);
        f16x8 pa1 = *(const f16x8*)(qB + (16 * mt + col) * KST + 32 + quad * 8);
        f16x8 pa2 = *(const f16x8*)(qB + (16 * mt + col) * KST + 64 + quad * 8);
        #pragma unroll
        for (int nt = 0; nt < 4; nt++) {
            f32x4 acc = {0.f, 0.f, 0.f, 0.f};
            const _Float16* tvrow = tvT + (16 * nt + col) * KST;
            acc = __builtin_amdgcn_mfma_f32_16x16x32_f16(pa0, *(const f16x8*)(tvrow + quad * 8), acc, 0, 0, 0);
            acc = __builtin_amdgcn_mfma_f32_16x16x32_f16(pa1, *(const f16x8*)(tvrow + 32 + quad * 8), acc, 0, 0, 0);
            acc = __builtin_amdgcn_mfma_f32_16x16x32_f16(pa2, *(const f16x8*)(tvrow + 64 + quad * 8), acc, 0, 0, 0);
            #pragma unroll
            for (int r = 0; r < 4; r++)
                loB[(16 * mt + quad * 4 + r) * LOST2 + 16 * nt + col] = (_Float16)tanh_f(acc[r]);
        }
    }
    __syncthreads();

    // xg2 = to @ l2_wih^T + biases -> GLOBAL f16 (24 tiles, 3 per wave)
    for (int i = 0; i < 3; i++) {
        const int flat = w + 8 * i;
        const int mt = flat >> 2, nt = flat & 3;
        const int g = 16 * nt + col;
        f32x4 acc = {0.f, 0.f, 0.f, 0.f};
        #pragma unroll
        for (int kc = 0; kc < 2; kc++) {
            f16x8 a  = *(const f16x8*)(&loB[(16 * mt + col) * LOST2 + kc * 32 + quad * 8]);
            f16x8 bb = frag_from_f32(l2_wih + g * HH + kc * 32 + quad * 8);
            acc = __builtin_amdgcn_mfma_f32_16x16x32_f16(a, bb, acc, 0, 0, 0);
        }
        const float bg2 = l2_bih[g] + l2_bhh[g];
        #pragma unroll
        for (int r = 0; r < 4; r++) {
            const int row = 16 * mt + quad * 4 + r;
            xg2[(size_t)b * SS * HH + row * HH + g] = (_Float16)(acc[r] + bg2);
        }
    }
}

// ---------------- Kernel 4: batched MFMA LSTM2 + fc ----------------
// 128 blocks x 64 thr (1 wave). Wave handles 16 batches (col=batch).
// Per step: G = xg2_init + Whh@h (4 MFMA, K=16 padded to 32), nonlin in-lane,
// h reshuffle via tiny LDS transpose (no barriers), fc via 1 MFMA.
__global__ __launch_bounds__(64) void k_lstm2(
    const _Float16* __restrict__ xg2,
    const float* __restrict__ l2_whh,
    const float* __restrict__ fc_w, const float* __restrict__ fc_b,
    float* __restrict__ out)
{
    __shared__ _Float16 xgS[8 * 16 * XGST];   // [s_l][n][72]
    __shared__ _Float16 hT[16 * HTST];        // [n][40], u>=16 zero (K-pad)

    const int bi = blockIdx.x;
    const int bg = bi * 16;
    const int lane = threadIdx.x;
    const int col = lane & 15, quad = lane >> 4;

    for (int i = lane; i < 16 * HTST / 2; i += 64) ((unsigned int*)hT)[i] = 0u;

    // A-frags: whh rows (16mt+col), K=16 real (quads 0-1), pad zero
    f16x8 wa[4];
    #pragma unroll
    for (int mt = 0; mt < 4; mt++) {
        f16x8 v;
        #pragma unroll
        for (int j = 0; j < 8; j++) v[j] = (_Float16)0.0f;
        if (quad < 2) {
            const float* src = l2_whh + (16 * mt + col) * H2 + quad * 8;
            #pragma unroll
            for (int j = 0; j < 8; j++) v[j] = (_Float16)src[j];
        }
        wa[mt] = v;
    }
    // fc A-frag: rows = output d (col<7), K=16 real
    f16x8 fca;
    {
        f16x8 v;
        #pragma unroll
        for (int j = 0; j < 8; j++) v[j] = (_Float16)0.0f;
        if (quad < 2 && col < DD) {
            const float* src = fc_w + col * H2 + quad * 8;
            #pragma unroll
            for (int j = 0; j < 8; j++) v[j] = (_Float16)src[j];
        }
        fca = v;
    }
    // fc bias for this lane's d rows
    float fcbr[4];
    #pragma unroll
    for (int r = 0; r < 4; r++) {
        const int d = quad * 4 + r;
        fcbr[r] = (d < DD) ? fc_b[d] : 0.0f;
    }

    float c[4] = {0.f, 0.f, 0.f, 0.f};
    f16x8 hfrag;
    #pragma unroll
    for (int j = 0; j < 8; j++) hfrag[j] = (_Float16)0.0f;

    for (int s0 = 0; s0 < SS; s0 += 8) {
        // stage 16 batches x 8 steps x 64 gates (f16)
        #pragma unroll
        for (int i = 0; i < 16; i++) {
            int fl = i * 64 + lane;            // [0,1024) f16x8 granules
            int n = fl >> 6, r6 = fl & 63;
            int s_l = r6 >> 3, c8 = r6 & 7;
            f16x8 v = *(const f16x8*)(xg2 + ((size_t)(bg + n) * SS + s0 + s_l) * HH + c8 * 8);
            *(f16x8*)(&xgS[(s_l * 16 + n) * XGST + c8 * 8]) = v;
        }

        for (int sl = 0; sl < 8; sl++) {
            const int s = s0 + sl;
            f32x4 g[4];
            #pragma unroll
            for (int mt = 0; mt < 4; mt++) {
                f16x4 xi = *(const f16x4*)(&xgS[(sl * 16 + col) * XGST + 16 * mt + 4 * quad]);
                f32x4 acc;
                acc[0] = (float)xi[0]; acc[1] = (float)xi[1];
                acc[2] = (float)xi[2]; acc[3] = (float)xi[3];
                g[mt] = __builtin_amdgcn_mfma_f32_16x16x32_f16(wa[mt], hfrag, acc, 0, 0, 0);
            }
            f16x4 hq;
            #pragma unroll
            for (int r = 0; r < 4; r++) {
                float iv = sigm(g[0][r]);
                float fv = sigm(g[1][r]);
                float gv = tanh_f(g[2][r]);
                float ov = sigm(g[3][r]);
                c[r] = fv * c[r] + iv * gv;
                hq[r] = (_Float16)(ov * tanh_f(c[r]));
            }
            *(f16x4*)(&hT[col * HTST + 4 * quad]) = hq;   // h[u=4q+r][batch col] -> hT[col][u]
            hfrag = *(const f16x8*)(&hT[col * HTST + quad * 8]);  // B[n=col][k=quad*8+j]
            // fc: D[d=quad*4+r][batch=col]
            f32x4 oz = {0.f, 0.f, 0.f, 0.f};
            f32x4 oacc = __builtin_amdgcn_mfma_f32_16x16x32_f16(fca, hfrag, oz, 0, 0, 0);
            float* op = out + ((size_t)(bg + col) * SS + s) * DD;
            #pragma unroll
            for (int r = 0; r < 4; r++) {
                const int d = quad * 4 + r;
                if (d < DD) op[d] = oacc[r] + fcbr[r];
            }
        }
    }
}

extern "C" void kernel_launch(void* const* d_in, const int* in_sizes, int n_in,
                              void* d_out, int out_size, void* d_ws, size_t ws_size,
                              hipStream_t stream) {
    const float* x     = (const float*)d_in[0];
    const float* fv_w  = (const float*)d_in[1];
    const float* fv_b  = (const float*)d_in[2];
    const float* fk_w  = (const float*)d_in[3];
    const float* fk_b  = (const float*)d_in[4];
    const float* fq_w  = (const float*)d_in[5];
    const float* fq_b  = (const float*)d_in[6];
    const float* l1f_wih = (const float*)d_in[7];
    const float* l1f_whh = (const float*)d_in[8];
    const float* l1f_bih = (const float*)d_in[9];
    const float* l1f_bhh = (const float*)d_in[10];
    const float* l1b_wih = (const float*)d_in[11];
    const float* l1b_whh = (const float*)d_in[12];
    const float* l1b_bih = (const float*)d_in[13];
    const float* l1b_bhh = (const float*)d_in[14];
    const float* tv_w  = (const float*)d_in[15];
    const float* tv_b  = (const float*)d_in[16];
    const float* tk_w  = (const float*)d_in[17];
    const float* tk_b  = (const float*)d_in[18];
    const float* tq_w  = (const float*)d_in[19];
    const float* tq_b  = (const float*)d_in[20];
    const float* l2_wih = (const float*)d_in[21];
    const float* l2_whh = (const float*)d_in[22];
    const float* l2_bih = (const float*)d_in[23];
    const float* l2_bhh = (const float*)d_in[24];
    const float* fc_w  = (const float*)d_in[25];
    const float* fc_b  = (const float*)d_in[26];

    float* fa = (float*)d_ws;                              // B*S*D fp32
    _Float16* hf = (_Float16*)(fa + (size_t)BB * SS * DD); // B*S*H f16
    _Float16* hb = hf + (size_t)BB * SS * HH;              // B*S*H f16
    _Float16* xg2 = hf;  // overlay: k_attn block b reads hf[b] first, writes xg2[b] last

    k_feat<<<BB, 256, 0, stream>>>(x, fv_w, fv_b, fk_w, fk_b, fq_w, fq_b, fa);
    k_bilstm<<<512, 256, 0, stream>>>(fa,
        l1f_wih, l1f_whh, l1f_bih, l1f_bhh,
        l1b_wih, l1b_whh, l1b_bih, l1b_bhh, hf, hb);
    k_attn<<<BB, 512, 0, stream>>>(hf, hb,
        tv_w, tv_b, tk_w, tk_b, tq_w, tq_b,
        l2_wih, l2_bih, l2_bhh, xg2);
    k_lstm2<<<128, 64, 0, stream>>>(xg2, l2_whh, fc_w, fc_b, (float*)d_out);
}

// Round 11
// 459.363 us; speedup vs baseline: 2.2805x; 1.0050x over previous
//
#include <hip/hip_runtime.h>
#include <math.h>

#define BB 2048
#define SS 96
#define DD 7
#define HH 64
#define H2 16
#define FASTR 776  // k_bilstm faS row stride (f16)
#define HST2 72    // k_bilstm h dbuf row stride (f16)
#define LOST2 88   // k_attn loB f16 stride (44 dw % 32 = 12 -> 2-way, free)
#define KST 120    // k_attn qB/tkS/tvT f16 stride (60 dw % 32 = 28 -> 2-way)
#define XGST 72    // k_lstm2 xgS staging stride (f16) per (s,n) row
#define HTST 40    // k_lstm2 hT stride (f16), cols 16..39 stay zero (K-pad)

typedef _Float16 f16x8 __attribute__((ext_vector_type(8)));
typedef _Float16 f16x4 __attribute__((ext_vector_type(4)));
typedef float f32x4 __attribute__((ext_vector_type(4)));

__device__ __forceinline__ float sigm(float x) { return 1.0f / (1.0f + __expf(-x)); }
__device__ __forceinline__ float tanh_f(float x) { return 1.0f - 2.0f / (__expf(2.0f * x) + 1.0f); }
__device__ __forceinline__ float rl(float v, int l) {
    return __int_as_float(__builtin_amdgcn_readlane(__float_as_int(v), l));
}
// load 8 consecutive fp32 (16B-aligned) -> f16x8 fragment
__device__ __forceinline__ f16x8 frag_from_f32(const float* base) {
    const float4* p = (const float4*)base;
    float4 a = p[0], b = p[1];
    f16x8 r;
    r[0] = (_Float16)a.x; r[1] = (_Float16)a.y; r[2] = (_Float16)a.z; r[3] = (_Float16)a.w;
    r[4] = (_Float16)b.x; r[5] = (_Float16)b.y; r[6] = (_Float16)b.z; r[7] = (_Float16)b.w;
    return r;
}

// ---------------- Kernel 1: feature attention (unchanged) ----------------
__global__ __launch_bounds__(256) void k_feat(
    const float* __restrict__ x,
    const float* __restrict__ fv_w, const float* __restrict__ fv_b,
    const float* __restrict__ fk_w, const float* __restrict__ fk_b,
    const float* __restrict__ fq_w, const float* __restrict__ fq_b,
    float* __restrict__ fa_out)
{
    __shared__ float xs[SS * DD], vs[SS * DD], ks[SS * DD], qs[SS * DD];
    __shared__ float att[DD * DD];
    __shared__ float wv[DD * DD], wk[DD * DD], wq[DD * DD];
    __shared__ float bv[DD], bk[DD], bq[DD];
    const int b = blockIdx.x, t = threadIdx.x;
    const float* xb = x + (size_t)b * SS * DD;

    for (int idx = t; idx < SS * DD; idx += 256) xs[idx] = xb[idx];
    if (t < DD * DD) { wv[t] = fv_w[t]; wk[t] = fk_w[t]; wq[t] = fq_w[t]; }
    if (t < DD)      { bv[t] = fv_b[t]; bk[t] = fk_b[t]; bq[t] = fq_b[t]; }
    __syncthreads();

    for (int idx = t; idx < SS * DD; idx += 256) {
        int s = idx / DD, j = idx % DD;
        float a = bv[j];
        #pragma unroll
        for (int i = 0; i < DD; i++) a += xs[s * DD + i] * wv[j * DD + i];
        vs[idx] = a;
    }
    __syncthreads();
    for (int idx = t; idx < SS * DD; idx += 256) {
        int s = idx / DD, j = idx % DD;
        float a = bk[j];
        #pragma unroll
        for (int i = 0; i < DD; i++) a += (xs[s * DD + i] + vs[s * DD + i]) * wk[j * DD + i];
        ks[idx] = a;
    }
    __syncthreads();
    for (int idx = t; idx < SS * DD; idx += 256) {
        int s = idx / DD, j = idx % DD;
        float a = bq[j];
        #pragma unroll
        for (int i = 0; i < DD; i++) a += (xs[s * DD + i] + ks[s * DD + i]) * wq[j * DD + i];
        qs[idx] = a;
    }
    __syncthreads();
    if (t < DD * DD) {
        int i = t / DD, j = t % DD;
        float a = 0.0f;
        for (int s = 0; s < SS; s++) a += qs[s * DD + i] * ks[s * DD + j];
        att[t] = a;
    }
    __syncthreads();
    if (t < DD) {
        float m = -1e30f;
        #pragma unroll
        for (int j = 0; j < DD; j++) m = fmaxf(m, att[t * DD + j]);
        float e[DD]; float sum = 0.0f;
        #pragma unroll
        for (int j = 0; j < DD; j++) { e[j] = __expf(att[t * DD + j] - m); sum += e[j]; }
        float inv = 1.0f / sum;
        #pragma unroll
        for (int j = 0; j < DD; j++) att[t * DD + j] = e[j] * inv;
    }
    __syncthreads();
    for (int idx = t; idx < SS * DD; idx += 256) {
        int s = idx / DD, j = idx % DD;
        float a = xs[idx];
        #pragma unroll
        for (int i = 0; i < DD; i++) a += vs[s * DD + i] * att[i * DD + j];
        fa_out[(size_t)b * SS * DD + idx] = tanh_f(a);
    }
}

// ---------------- Kernel 2: MFMA-batched bidirectional LSTM ----------------
// launch_bounds(256,2): 2 blocks/CU floor -> 128-VGPR budget so the 12 weight
// fragments (48 VGPRs) stay RESIDENT (VGPR=60 last round = compiler demoted
// them to per-step global reloads; this is the fix).
__global__ __launch_bounds__(256, 2) void k_bilstm(
    const float* __restrict__ fa,
    const float* __restrict__ wih_f, const float* __restrict__ whh_f,
    const float* __restrict__ bih_f, const float* __restrict__ bhh_f,
    const float* __restrict__ wih_b, const float* __restrict__ whh_b,
    const float* __restrict__ bih_b, const float* __restrict__ bhh_b,
    _Float16* __restrict__ hf, _Float16* __restrict__ hb)
{
    __shared__ _Float16 faS[16 * FASTR];
    __shared__ _Float16 hS[2][16 * HST2];

    const int bx = blockIdx.x;
    const int bg = bx >> 1, dir = bx & 1;
    const int t = threadIdx.x, lane = t & 63, w = t >> 6;
    const int col = lane & 15, quad = lane >> 4;

    const float* wih = dir ? wih_b : wih_f;
    const float* whh = dir ? whh_b : whh_f;
    const float* bih = dir ? bih_b : bih_f;
    const float* bhh = dir ? bhh_b : bhh_f;
    _Float16* hout = dir ? hb : hf;

    for (int i = t; i < 16 * FASTR / 2; i += 256) ((unsigned int*)faS)[i] = 0u;
    for (int i = t; i < 2 * 16 * HST2 / 2; i += 256) ((unsigned int*)hS)[i] = 0u;

    f16x8 wh[4][2];
    f16x8 wi[4];
    #pragma unroll
    for (int gt = 0; gt < 4; gt++) {
        const int row = 16 * (w + 4 * gt) + col;
        wh[gt][0] = frag_from_f32(whh + row * HH + quad * 8);
        wh[gt][1] = frag_from_f32(whh + row * HH + 32 + quad * 8);
        f16x8 v;
        #pragma unroll
        for (int j = 0; j < 8; j++) v[j] = (_Float16)0.0f;
        if (quad == 0) {
            #pragma unroll
            for (int j = 0; j < DD; j++) v[j] = (_Float16)wih[row * DD + j];
            v[7] = (_Float16)(bih[row] + bhh[row]);
        }
        wi[gt] = v;
    }
    __syncthreads();

    const float* fab = fa + (size_t)(bg * 8) * SS * DD;
    for (int idx = t; idx < 8 * SS * DD; idx += 256) {
        int n = idx / (SS * DD), r = idx % (SS * DD);
        int s = r / DD, i = r % DD;
        faS[n * FASTR + s * 8 + i] = (_Float16)fab[idx];
    }
    for (int idx = t; idx < 8 * SS; idx += 256) {
        int n = idx / SS, s = idx % SS;
        faS[n * FASTR + s * 8 + 7] = (_Float16)1.0f;
    }
    __syncthreads();

    // hoisted global-store pointers (incremented by +/- HH per step)
    _Float16* hp0;
    _Float16* hp1;
    {
        const int n0 = t >> 6, u0 = t & 63;
        const int n1 = (t + 256) >> 6, u1 = (t + 256) & 63;
        const int s_init = dir ? (SS - 1) : 0;
        hp0 = hout + ((size_t)(bg * 8 + n0)) * SS * HH + s_init * HH + u0;
        hp1 = hout + ((size_t)(bg * 8 + n1)) * SS * HH + s_init * HH + u1;
    }
    const int sstep = dir ? -HH : HH;
    const int hidx0 = (t >> 6) * HST2 + (t & 63);
    const int hidx1 = ((t + 256) >> 6) * HST2 + ((t + 256) & 63);

    float c0 = 0.f, c1 = 0.f, c2 = 0.f, c3 = 0.f;

    for (int step = 0; step < SS; step++) {
        const int s = dir ? (SS - 1 - step) : step;
        const int p = step & 1;

        // prefetch fa fragment (independent of h)
        f16x8 faf;
        #pragma unroll
        for (int j = 0; j < 8; j++) faf[j] = (_Float16)0.0f;
        if (quad == 0) faf = *(const f16x8*)(&faS[col * FASTR + s * 8]);

        f16x8 h0 = *(const f16x8*)(&hS[p][col * HST2 + quad * 8]);
        f16x8 h1 = *(const f16x8*)(&hS[p][col * HST2 + 32 + quad * 8]);

        f32x4 g[4];
        #pragma unroll
        for (int gt = 0; gt < 4; gt++) {
            f32x4 acc = {0.f, 0.f, 0.f, 0.f};
            acc = __builtin_amdgcn_mfma_f32_16x16x32_f16(wi[gt], faf, acc, 0, 0, 0);
            acc = __builtin_amdgcn_mfma_f32_16x16x32_f16(wh[gt][0], h0, acc, 0, 0, 0);
            acc = __builtin_amdgcn_mfma_f32_16x16x32_f16(wh[gt][1], h1, acc, 0, 0, 0);
            g[gt] = acc;
        }
        f16x4 hq;
        {
            float iv, fv, gv, ov, hv;
            iv = sigm(g[0][0]); fv = sigm(g[1][0]); gv = tanh_f(g[2][0]); ov = sigm(g[3][0]);
            c0 = fv * c0 + iv * gv; hv = ov * tanh_f(c0); hq[0] = (_Float16)hv;
            iv = sigm(g[0][1]); fv = sigm(g[1][1]); gv = tanh_f(g[2][1]); ov = sigm(g[3][1]);
            c1 = fv * c1 + iv * gv; hv = ov * tanh_f(c1); hq[1] = (_Float16)hv;
            iv = sigm(g[0][2]); fv = sigm(g[1][2]); gv = tanh_f(g[2][2]); ov = sigm(g[3][2]);
            c2 = fv * c2 + iv * gv; hv = ov * tanh_f(c2); hq[2] = (_Float16)hv;
            iv = sigm(g[0][3]); fv = sigm(g[1][3]); gv = tanh_f(g[2][3]); ov = sigm(g[3][3]);
            c3 = fv * c3 + iv * gv; hv = ov * tanh_f(c3); hq[3] = (_Float16)hv;
        }
        *(f16x4*)(&hS[1 - p][col * HST2 + 16 * w + quad * 4]) = hq;
        __syncthreads();

        *hp0 = hS[1 - p][hidx0];
        *hp1 = hS[1 - p][hidx1];
        hp0 += sstep;
        hp1 += sstep;
    }
}

// ---------------- Kernel 3: temporal attention (MFMA f16, unchanged) ----------------
__global__ __launch_bounds__(512, 2) void k_attn(
    const _Float16* __restrict__ hf, const _Float16* __restrict__ hb,
    const float* __restrict__ tv_w, const float* __restrict__ tv_b,
    const float* __restrict__ tk_w, const float* __restrict__ tk_b,
    const float* __restrict__ tq_w, const float* __restrict__ tq_b,
    const float* __restrict__ l2_wih,
    const float* __restrict__ l2_bih, const float* __restrict__ l2_bhh,
    _Float16* __restrict__ xg2)
{
    __shared__ _Float16 loB[SS * LOST2];   // lo -> 'to'
    __shared__ _Float16 qB[SS * KST];      // q[s][f] -> p[s][P]
    __shared__ _Float16 tkS[SS * KST];     // tk[s][f]
    __shared__ _Float16 tvT[HH * KST];     // tv^T[d][P]

    const int b = blockIdx.x, t = threadIdx.x;
    const int lane = t & 63, w = t >> 6;
    const int col = lane & 15, quad = lane >> 4;

    const _Float16* hfp = hf + (size_t)b * SS * HH;
    const _Float16* hbp = hb + (size_t)b * SS * HH;
    for (int g8 = t; g8 < 768; g8 += 512) {
        f16x8 va = *(const f16x8*)(hfp + g8 * 8);
        f16x8 vb = *(const f16x8*)(hbp + g8 * 8);
        int s = g8 >> 3, d = (g8 & 7) * 8;
        f16x8 r;
        #pragma unroll
        for (int j = 0; j < 8; j++) r[j] = (_Float16)(0.5f * ((float)va[j] + (float)vb[j]));
        *(f16x8*)(&loB[s * LOST2 + d]) = r;
    }
    __syncthreads();

    for (int i = 0; i < 9; i++) {
        const int flat = w + 8 * i;
        const int proj = flat / 24, rem = flat % 24;
        const int mt = rem >> 2, nt = rem & 3;
        const float* wmat = (proj == 0) ? tv_w : (proj == 1) ? tk_w : tq_w;
        const float* bvec = (proj == 0) ? tv_b : (proj == 1) ? tk_b : tq_b;
        const int j = 16 * nt + col;
        f32x4 acc = {0.f, 0.f, 0.f, 0.f};
        #pragma unroll
        for (int kc = 0; kc < 2; kc++) {
            f16x8 a  = *(const f16x8*)(&loB[(16 * mt + col) * LOST2 + kc * 32 + quad * 8]);
            f16x8 bb = frag_from_f32(wmat + j * HH + kc * 32 + quad * 8);
            acc = __builtin_amdgcn_mfma_f32_16x16x32_f16(a, bb, acc, 0, 0, 0);
        }
        const float bj = bvec[j];
        #pragma unroll
        for (int r = 0; r < 4; r++) {
            const float v = acc[r] + bj;
            const int row = 16 * mt + quad * 4 + r;
            if (proj == 0)      tvT[j * KST + row] = (_Float16)v;
            else if (proj == 1) tkS[row * KST + j] = (_Float16)v;
            else                qB[row * KST + j]  = (_Float16)v;
        }
    }
    __syncthreads();

    if (w < 6) {
        const int mt = w;
        f16x8 aq0 = *(const f16x8*)(qB + (16 * mt + col) * KST + quad * 8);
        f16x8 aq1 = *(const f16x8*)(qB + (16 * mt + col) * KST + 32 + quad * 8);
        f32x4 sc[6];
        #pragma unroll
        for (int nt = 0; nt < 6; nt++) {
            f32x4 acc = {0.f, 0.f, 0.f, 0.f};
            f16x8 b0 = *(const f16x8*)(tkS + (16 * nt + col) * KST + quad * 8);
            f16x8 b1 = *(const f16x8*)(tkS + (16 * nt + col) * KST + 32 + quad * 8);
            acc = __builtin_amdgcn_mfma_f32_16x16x32_f16(aq0, b0, acc, 0, 0, 0);
            acc = __builtin_amdgcn_mfma_f32_16x16x32_f16(aq1, b1, acc, 0, 0, 0);
            sc[nt] = acc;
        }
        #pragma unroll
        for (int r = 0; r < 4; r++) {
            float m = sc[0][r];
            #pragma unroll
            for (int nt = 1; nt < 6; nt++) m = fmaxf(m, sc[nt][r]);
            #pragma unroll
            for (int o = 1; o < 16; o <<= 1) m = fmaxf(m, __shfl_xor(m, o));
            float e[6]; float sum = 0.0f;
            #pragma unroll
            for (int nt = 0; nt < 6; nt++) { e[nt] = __expf(sc[nt][r] - m); sum += e[nt]; }
            #pragma unroll
            for (int o = 1; o < 16; o <<= 1) sum += __shfl_xor(sum, o);
            const float inv = 1.0f / sum;
            const int row = 16 * mt + quad * 4 + r;
            #pragma unroll
            for (int nt = 0; nt < 6; nt++)
                qB[row * KST + 16 * nt + col] = (_Float16)(e[nt] * inv);
        }
        f16x8 pa0 = *(const f16x8*)(qB + (16 * mt + col) * KST + quad * 8);
        f16x8 pa1 = *(const f16x8*)(qB + (16 * mt + col) * KST + 32 + quad * 8);
        f16x8 pa2 = *(const f16x8*)(qB + (16 * mt + col) * KST + 64 + quad * 8);
        #pragma unroll
        for (int nt = 0; nt < 4; nt++) {
            f32x4 acc = {0.f, 0.f, 0.f, 0.f};
            const _Float16* tvrow = tvT + (16 * nt + col) * KST;
            acc = __builtin_amdgcn_mfma_f32_16x16x32_f16(pa0, *(const f16x8*)(tvrow + quad * 8), acc, 0, 0, 0);
            acc = __builtin_amdgcn_mfma_f32_16x16x32_f16(pa1, *(const f16x8*)(tvrow + 32 + quad * 8), acc, 0, 0, 0);
            acc = __builtin_amdgcn_mfma_f32_16x16x32_f16(pa2, *(const f16x8*)(tvrow + 64 + quad * 8), acc, 0, 0, 0);
            #pragma unroll
            for (int r = 0; r < 4; r++)
                loB[(16 * mt + quad * 4 + r) * LOST2 + 16 * nt + col] = (_Float16)tanh_f(acc[r]);
        }
    }
    __syncthreads();

    for (int i = 0; i < 3; i++) {
        const int flat = w + 8 * i;
        const int mt = flat >> 2, nt = flat & 3;
        const int g = 16 * nt + col;
        f32x4 acc = {0.f, 0.f, 0.f, 0.f};
        #pragma unroll
        for (int kc = 0; kc < 2; kc++) {
            f16x8 a  = *(const f16x8*)(&loB[(16 * mt + col) * LOST2 + kc * 32 + quad * 8]);
            f16x8 bb = frag_from_f32(l2_wih + g * HH + kc * 32 + quad * 8);
            acc = __builtin_amdgcn_mfma_f32_16x16x32_f16(a, bb, acc, 0, 0, 0);
        }
        const float bg2 = l2_bih[g] + l2_bhh[g];
        #pragma unroll
        for (int r = 0; r < 4; r++) {
            const int row = 16 * mt + quad * 4 + r;
            xg2[(size_t)b * SS * HH + row * HH + g] = (_Float16)(acc[r] + bg2);
        }
    }
}

// ---------------- Kernel 4: batched MFMA LSTM2 + fc (unchanged) ----------------
__global__ __launch_bounds__(64) void k_lstm2(
    const _Float16* __restrict__ xg2,
    const float* __restrict__ l2_whh,
    const float* __restrict__ fc_w, const float* __restrict__ fc_b,
    float* __restrict__ out)
{
    __shared__ _Float16 xgS[8 * 16 * XGST];   // [s_l][n][72]
    __shared__ _Float16 hT[16 * HTST];        // [n][40], u>=16 zero (K-pad)

    const int bi = blockIdx.x;
    const int bg = bi * 16;
    const int lane = threadIdx.x;
    const int col = lane & 15, quad = lane >> 4;

    for (int i = lane; i < 16 * HTST / 2; i += 64) ((unsigned int*)hT)[i] = 0u;

    f16x8 wa[4];
    #pragma unroll
    for (int mt = 0; mt < 4; mt++) {
        f16x8 v;
        #pragma unroll
        for (int j = 0; j < 8; j++) v[j] = (_Float16)0.0f;
        if (quad < 2) {
            const float* src = l2_whh + (16 * mt + col) * H2 + quad * 8;
            #pragma unroll
            for (int j = 0; j < 8; j++) v[j] = (_Float16)src[j];
        }
        wa[mt] = v;
    }
    f16x8 fca;
    {
        f16x8 v;
        #pragma unroll
        for (int j = 0; j < 8; j++) v[j] = (_Float16)0.0f;
        if (quad < 2 && col < DD) {
            const float* src = fc_w + col * H2 + quad * 8;
            #pragma unroll
            for (int j = 0; j < 8; j++) v[j] = (_Float16)src[j];
        }
        fca = v;
    }
    float fcbr[4];
    #pragma unroll
    for (int r = 0; r < 4; r++) {
        const int d = quad * 4 + r;
        fcbr[r] = (d < DD) ? fc_b[d] : 0.0f;
    }

    float c[4] = {0.f, 0.f, 0.f, 0.f};
    f16x8 hfrag;
    #pragma unroll
    for (int j = 0; j < 8; j++) hfrag[j] = (_Float16)0.0f;

    for (int s0 = 0; s0 < SS; s0 += 8) {
        #pragma unroll
        for (int i = 0; i < 16; i++) {
            int fl = i * 64 + lane;
            int n = fl >> 6, r6 = fl & 63;
            int s_l = r6 >> 3, c8 = r6 & 7;
            f16x8 v = *(const f16x8*)(xg2 + ((size_t)(bg + n) * SS + s0 + s_l) * HH + c8 * 8);
            *(f16x8*)(&xgS[(s_l * 16 + n) * XGST + c8 * 8]) = v;
        }

        for (int sl = 0; sl < 8; sl++) {
            const int s = s0 + sl;
            f32x4 g[4];
            #pragma unroll
            for (int mt = 0; mt < 4; mt++) {
                f16x4 xi = *(const f16x4*)(&xgS[(sl * 16 + col) * XGST + 16 * mt + 4 * quad]);
                f32x4 acc;
                acc[0] = (float)xi[0]; acc[1] = (float)xi[1];
                acc[2] = (float)xi[2]; acc[3] = (float)xi[3];
                g[mt] = __builtin_amdgcn_mfma_f32_16x16x32_f16(wa[mt], hfrag, acc, 0, 0, 0);
            }
            f16x4 hq;
            #pragma unroll
            for (int r = 0; r < 4; r++) {
                float iv = sigm(g[0][r]);
                float fv = sigm(g[1][r]);
                float gv = tanh_f(g[2][r]);
                float ov = sigm(g[3][r]);
                c[r] = fv * c[r] + iv * gv;
                hq[r] = (_Float16)(ov * tanh_f(c[r]));
            }
            *(f16x4*)(&hT[col * HTST + 4 * quad]) = hq;
            hfrag = *(const f16x8*)(&hT[col * HTST + quad * 8]);
            f32x4 oz = {0.f, 0.f, 0.f, 0.f};
            f32x4 oacc = __builtin_amdgcn_mfma_f32_16x16x32_f16(fca, hfrag, oz, 0, 0, 0);
            float* op = out + ((size_t)(bg + col) * SS + s) * DD;
            #pragma unroll
            for (int r = 0; r < 4; r++) {
                const int d = quad * 4 + r;
                if (d < DD) op[d] = oacc[r] + fcbr[r];
            }
        }
    }
}

extern "C" void kernel_launch(void* const* d_in, const int* in_sizes, int n_in,
                              void* d_out, int out_size, void* d_ws, size_t ws_size,
                              hipStream_t stream) {
    const float* x     = (const float*)d_in[0];
    const float* fv_w  = (const float*)d_in[1];
    const float* fv_b  = (const float*)d_in[2];
    const float* fk_w  = (const float*)d_in[3];
    const float* fk_b  = (const float*)d_in[4];
    const float* fq_w  = (const float*)d_in[5];
    const float* fq_b  = (const float*)d_in[6];
    const float* l1f_wih = (const float*)d_in[7];
    const float* l1f_whh = (const float*)d_in[8];
    const float* l1f_bih = (const float*)d_in[9];
    const float* l1f_bhh = (const float*)d_in[10];
    const float* l1b_wih = (const float*)d_in[11];
    const float* l1b_whh = (const float*)d_in[12];
    const float* l1b_bih = (const float*)d_in[13];
    const float* l1b_bhh = (const float*)d_in[14];
    const float* tv_w  = (const float*)d_in[15];
    const float* tv_b  = (const float*)d_in[16];
    const float* tk_w  = (const float*)d_in[17];
    const float* tk_b  = (const float*)d_in[18];
    const float* tq_w  = (const float*)d_in[19];
    const float* tq_b  = (const float*)d_in[20];
    const float* l2_wih = (const float*)d_in[21];
    const float* l2_whh = (const float*)d_in[22];
    const float* l2_bih = (const float*)d_in[23];
    const float* l2_bhh = (const float*)d_in[24];
    const float* fc_w  = (const float*)d_in[25];
    const float* fc_b  = (const float*)d_in[26];

    float* fa = (float*)d_ws;                              // B*S*D fp32
    _Float16* hf = (_Float16*)(fa + (size_t)BB * SS * DD); // B*S*H f16
    _Float16* hb = hf + (size_t)BB * SS * HH;              // B*S*H f16
    _Float16* xg2 = hf;  // overlay: k_attn block b reads hf[b] first, writes xg2[b] last

    k_feat<<<BB, 256, 0, stream>>>(x, fv_w, fv_b, fk_w, fk_b, fq_w, fq_b, fa);
    k_bilstm<<<512, 256, 0, stream>>>(fa,
        l1f_wih, l1f_whh, l1f_bih, l1f_bhh,
        l1b_wih, l1b_whh, l1b_bih, l1b_bhh, hf, hb);
    k_attn<<<BB, 512, 0, stream>>>(hf, hb,
        tv_w, tv_b, tk_w, tk_b, tq_w, tq_b,
        l2_wih, l2_bih, l2_bhh, xg2);
    k_lstm2<<<128, 64, 0, stream>>>(xg2, l2_whh, fc_w, fc_b, (float*)d_out);
}

// Round 12
// 394.059 us; speedup vs baseline: 2.6584x; 1.1657x over previous
//
#include <hip/hip_runtime.h>
#include <math.h>

#define BB 2048
#define SS 96
#define DD 7
#define HH 64
#define H2 16
#define FASTR 776  // k_bilstm faS row stride (f16)
#define HST2 72    // k_bilstm h dbuf row stride (f16)
#define LOST2 88   // k_attn loB f16 stride (44 dw % 32 = 12 -> 2-way, free)
#define KST 120    // k_attn qB/tkS/tvT f16 stride (60 dw % 32 = 28 -> 2-way)
#define XGST 72    // k_lstm2 xgS staging stride (f16) per (s,n) row
#define HTST 40    // k_lstm2 hT stride (f16), cols 16..39 stay zero (K-pad)

typedef _Float16 f16x8 __attribute__((ext_vector_type(8)));
typedef _Float16 f16x4 __attribute__((ext_vector_type(4)));
typedef float f32x4 __attribute__((ext_vector_type(4)));

__device__ __forceinline__ float sigm(float x) { return 1.0f / (1.0f + __expf(-x)); }
__device__ __forceinline__ float tanh_f(float x) { return 1.0f - 2.0f / (__expf(2.0f * x) + 1.0f); }
__device__ __forceinline__ float rl(float v, int l) {
    return __int_as_float(__builtin_amdgcn_readlane(__float_as_int(v), l));
}
// load 8 consecutive fp32 (16B-aligned) -> f16x8 fragment
__device__ __forceinline__ f16x8 frag_from_f32(const float* base) {
    const float4* p = (const float4*)base;
    float4 a = p[0], b = p[1];
    f16x8 r;
    r[0] = (_Float16)a.x; r[1] = (_Float16)a.y; r[2] = (_Float16)a.z; r[3] = (_Float16)a.w;
    r[4] = (_Float16)b.x; r[5] = (_Float16)b.y; r[6] = (_Float16)b.z; r[7] = (_Float16)b.w;
    return r;
}

// ---------------- Kernel 1: feature attention (unchanged) ----------------
__global__ __launch_bounds__(256) void k_feat(
    const float* __restrict__ x,
    const float* __restrict__ fv_w, const float* __restrict__ fv_b,
    const float* __restrict__ fk_w, const float* __restrict__ fk_b,
    const float* __restrict__ fq_w, const float* __restrict__ fq_b,
    float* __restrict__ fa_out)
{
    __shared__ float xs[SS * DD], vs[SS * DD], ks[SS * DD], qs[SS * DD];
    __shared__ float att[DD * DD];
    __shared__ float wv[DD * DD], wk[DD * DD], wq[DD * DD];
    __shared__ float bv[DD], bk[DD], bq[DD];
    const int b = blockIdx.x, t = threadIdx.x;
    const float* xb = x + (size_t)b * SS * DD;

    for (int idx = t; idx < SS * DD; idx += 256) xs[idx] = xb[idx];
    if (t < DD * DD) { wv[t] = fv_w[t]; wk[t] = fk_w[t]; wq[t] = fq_w[t]; }
    if (t < DD)      { bv[t] = fv_b[t]; bk[t] = fk_b[t]; bq[t] = fq_b[t]; }
    __syncthreads();

    for (int idx = t; idx < SS * DD; idx += 256) {
        int s = idx / DD, j = idx % DD;
        float a = bv[j];
        #pragma unroll
        for (int i = 0; i < DD; i++) a += xs[s * DD + i] * wv[j * DD + i];
        vs[idx] = a;
    }
    __syncthreads();
    for (int idx = t; idx < SS * DD; idx += 256) {
        int s = idx / DD, j = idx % DD;
        float a = bk[j];
        #pragma unroll
        for (int i = 0; i < DD; i++) a += (xs[s * DD + i] + vs[s * DD + i]) * wk[j * DD + i];
        ks[idx] = a;
    }
    __syncthreads();
    for (int idx = t; idx < SS * DD; idx += 256) {
        int s = idx / DD, j = idx % DD;
        float a = bq[j];
        #pragma unroll
        for (int i = 0; i < DD; i++) a += (xs[s * DD + i] + ks[s * DD + i]) * wq[j * DD + i];
        qs[idx] = a;
    }
    __syncthreads();
    if (t < DD * DD) {
        int i = t / DD, j = t % DD;
        float a = 0.0f;
        for (int s = 0; s < SS; s++) a += qs[s * DD + i] * ks[s * DD + j];
        att[t] = a;
    }
    __syncthreads();
    if (t < DD) {
        float m = -1e30f;
        #pragma unroll
        for (int j = 0; j < DD; j++) m = fmaxf(m, att[t * DD + j]);
        float e[DD]; float sum = 0.0f;
        #pragma unroll
        for (int j = 0; j < DD; j++) { e[j] = __expf(att[t * DD + j] - m); sum += e[j]; }
        float inv = 1.0f / sum;
        #pragma unroll
        for (int j = 0; j < DD; j++) att[t * DD + j] = e[j] * inv;
    }
    __syncthreads();
    for (int idx = t; idx < SS * DD; idx += 256) {
        int s = idx / DD, j = idx % DD;
        float a = xs[idx];
        #pragma unroll
        for (int i = 0; i < DD; i++) a += vs[s * DD + i] * att[i * DD + j];
        fa_out[(size_t)b * SS * DD + idx] = tanh_f(a);
    }
}

// ---------------- Kernel 2: MFMA-batched bidirectional LSTM (16 real batches) ----------------
// grid 256 = 128 batch-groups x 2 dirs; block = 16 batches, 1 dir, 4 waves.
// Full 16-wide fragments (no padding waste). h stores software-pipelined from
// regs at loop top (full step to drain before barrier's vmcnt(0)).
__global__ __launch_bounds__(256, 2) void k_bilstm(
    const float* __restrict__ fa,
    const float* __restrict__ wih_f, const float* __restrict__ whh_f,
    const float* __restrict__ bih_f, const float* __restrict__ bhh_f,
    const float* __restrict__ wih_b, const float* __restrict__ whh_b,
    const float* __restrict__ bih_b, const float* __restrict__ bhh_b,
    _Float16* __restrict__ hf, _Float16* __restrict__ hb)
{
    __shared__ _Float16 faS[16 * FASTR];   // [n][s*8+i], i=7 holds 1.0
    __shared__ _Float16 hS[2][16 * HST2];  // h dbuf: [n][unit]

    const int bx = blockIdx.x;
    const int bg = bx >> 1, dir = bx & 1;
    const int t = threadIdx.x, lane = t & 63, w = t >> 6;
    const int col = lane & 15, quad = lane >> 4;

    const float* wih = dir ? wih_b : wih_f;
    const float* whh = dir ? whh_b : whh_f;
    const float* bih = dir ? bih_b : bih_f;
    const float* bhh = dir ? bhh_b : bhh_f;
    _Float16* hout = dir ? hb : hf;

    for (int i = t; i < 2 * 16 * HST2 / 2; i += 256) ((unsigned int*)hS)[i] = 0u;

    // resident weight fragments
    f16x8 wh[4][2];
    f16x8 wi[4];
    #pragma unroll
    for (int gt = 0; gt < 4; gt++) {
        const int row = 16 * (w + 4 * gt) + col;
        wh[gt][0] = frag_from_f32(whh + row * HH + quad * 8);
        wh[gt][1] = frag_from_f32(whh + row * HH + 32 + quad * 8);
        f16x8 v;
        #pragma unroll
        for (int j = 0; j < 8; j++) v[j] = (_Float16)0.0f;
        if (quad == 0) {
            #pragma unroll
            for (int j = 0; j < DD; j++) v[j] = (_Float16)wih[row * DD + j];
            v[7] = (_Float16)(bih[row] + bhh[row]);
        }
        wi[gt] = v;
    }

    // fill faS: 16 batches x 96 steps x 7 features + ones column
    const float* fab = fa + (size_t)(bg * 16) * SS * DD;
    for (int idx = t; idx < 16 * SS * DD; idx += 256) {
        int n = idx / (SS * DD), r = idx % (SS * DD);
        int s = r / DD, i = r % DD;
        faS[n * FASTR + s * 8 + i] = (_Float16)fab[idx];
    }
    for (int idx = t; idx < 16 * SS; idx += 256) {
        int n = idx / SS, s = idx % SS;
        faS[n * FASTR + s * 8 + 7] = (_Float16)1.0f;
    }
    __syncthreads();

    // pipelined store pointer: lane stores units 16w+4*quad..+3 for batch col
    const int sstep = dir ? -HH : HH;
    _Float16* hp = hout + ((size_t)(bg * 16 + col)) * SS * HH
                 + (dir ? (SS - 1) : 0) * HH + 16 * w + quad * 4;

    const f32x4 ZC = {0.f, 0.f, 0.f, 0.f};
    float c0 = 0.f, c1 = 0.f, c2 = 0.f, c3 = 0.f;
    f16x4 hq;

    for (int step = 0; step < SS; step++) {
        const int s = dir ? (SS - 1 - step) : step;
        const int p = step & 1;

        if (step) {                       // store PREV step's h from regs
            *(f16x4*)hp = hq;
            hp += sstep;
        }

        f16x8 faf;
        #pragma unroll
        for (int j = 0; j < 8; j++) faf[j] = (_Float16)0.0f;
        if (quad == 0) faf = *(const f16x8*)(&faS[col * FASTR + s * 8]);

        f16x8 h0 = *(const f16x8*)(&hS[p][col * HST2 + quad * 8]);
        f16x8 h1 = *(const f16x8*)(&hS[p][col * HST2 + 32 + quad * 8]);

        f32x4 g[4];
        #pragma unroll
        for (int gt = 0; gt < 4; gt++) {
            f32x4 acc = __builtin_amdgcn_mfma_f32_16x16x32_f16(wi[gt], faf, ZC, 0, 0, 0);
            acc = __builtin_amdgcn_mfma_f32_16x16x32_f16(wh[gt][0], h0, acc, 0, 0, 0);
            acc = __builtin_amdgcn_mfma_f32_16x16x32_f16(wh[gt][1], h1, acc, 0, 0, 0);
            g[gt] = acc;
        }
        {
            float iv, fv, gv, ov, hv;
            iv = sigm(g[0][0]); fv = sigm(g[1][0]); gv = tanh_f(g[2][0]); ov = sigm(g[3][0]);
            c0 = fv * c0 + iv * gv; hv = ov * tanh_f(c0); hq[0] = (_Float16)hv;
            iv = sigm(g[0][1]); fv = sigm(g[1][1]); gv = tanh_f(g[2][1]); ov = sigm(g[3][1]);
            c1 = fv * c1 + iv * gv; hv = ov * tanh_f(c1); hq[1] = (_Float16)hv;
            iv = sigm(g[0][2]); fv = sigm(g[1][2]); gv = tanh_f(g[2][2]); ov = sigm(g[3][2]);
            c2 = fv * c2 + iv * gv; hv = ov * tanh_f(c2); hq[2] = (_Float16)hv;
            iv = sigm(g[0][3]); fv = sigm(g[1][3]); gv = tanh_f(g[2][3]); ov = sigm(g[3][3]);
            c3 = fv * c3 + iv * gv; hv = ov * tanh_f(c3); hq[3] = (_Float16)hv;
        }
        *(f16x4*)(&hS[1 - p][col * HST2 + 16 * w + quad * 4]) = hq;
        __syncthreads();
    }
    *(f16x4*)hp = hq;                     // final step's h
}

// ---------------- Kernel 3: temporal attention (MFMA f16, unchanged) ----------------
__global__ __launch_bounds__(512, 2) void k_attn(
    const _Float16* __restrict__ hf, const _Float16* __restrict__ hb,
    const float* __restrict__ tv_w, const float* __restrict__ tv_b,
    const float* __restrict__ tk_w, const float* __restrict__ tk_b,
    const float* __restrict__ tq_w, const float* __restrict__ tq_b,
    const float* __restrict__ l2_wih,
    const float* __restrict__ l2_bih, const float* __restrict__ l2_bhh,
    _Float16* __restrict__ xg2)
{
    __shared__ _Float16 loB[SS * LOST2];   // lo -> 'to'
    __shared__ _Float16 qB[SS * KST];      // q[s][f] -> p[s][P]
    __shared__ _Float16 tkS[SS * KST];     // tk[s][f]
    __shared__ _Float16 tvT[HH * KST];     // tv^T[d][P]

    const int b = blockIdx.x, t = threadIdx.x;
    const int lane = t & 63, w = t >> 6;
    const int col = lane & 15, quad = lane >> 4;

    const _Float16* hfp = hf + (size_t)b * SS * HH;
    const _Float16* hbp = hb + (size_t)b * SS * HH;
    for (int g8 = t; g8 < 768; g8 += 512) {
        f16x8 va = *(const f16x8*)(hfp + g8 * 8);
        f16x8 vb = *(const f16x8*)(hbp + g8 * 8);
        int s = g8 >> 3, d = (g8 & 7) * 8;
        f16x8 r;
        #pragma unroll
        for (int j = 0; j < 8; j++) r[j] = (_Float16)(0.5f * ((float)va[j] + (float)vb[j]));
        *(f16x8*)(&loB[s * LOST2 + d]) = r;
    }
    __syncthreads();

    for (int i = 0; i < 9; i++) {
        const int flat = w + 8 * i;
        const int proj = flat / 24, rem = flat % 24;
        const int mt = rem >> 2, nt = rem & 3;
        const float* wmat = (proj == 0) ? tv_w : (proj == 1) ? tk_w : tq_w;
        const float* bvec = (proj == 0) ? tv_b : (proj == 1) ? tk_b : tq_b;
        const int j = 16 * nt + col;
        f32x4 acc = {0.f, 0.f, 0.f, 0.f};
        #pragma unroll
        for (int kc = 0; kc < 2; kc++) {
            f16x8 a  = *(const f16x8*)(&loB[(16 * mt + col) * LOST2 + kc * 32 + quad * 8]);
            f16x8 bb = frag_from_f32(wmat + j * HH + kc * 32 + quad * 8);
            acc = __builtin_amdgcn_mfma_f32_16x16x32_f16(a, bb, acc, 0, 0, 0);
        }
        const float bj = bvec[j];
        #pragma unroll
        for (int r = 0; r < 4; r++) {
            const float v = acc[r] + bj;
            const int row = 16 * mt + quad * 4 + r;
            if (proj == 0)      tvT[j * KST + row] = (_Float16)v;
            else if (proj == 1) tkS[row * KST + j] = (_Float16)v;
            else                qB[row * KST + j]  = (_Float16)v;
        }
    }
    __syncthreads();

    if (w < 6) {
        const int mt = w;
        f16x8 aq0 = *(const f16x8*)(qB + (16 * mt + col) * KST + quad * 8);
        f16x8 aq1 = *(const f16x8*)(qB + (16 * mt + col) * KST + 32 + quad * 8);
        f32x4 sc[6];
        #pragma unroll
        for (int nt = 0; nt < 6; nt++) {
            f32x4 acc = {0.f, 0.f, 0.f, 0.f};
            f16x8 b0 = *(const f16x8*)(tkS + (16 * nt + col) * KST + quad * 8);
            f16x8 b1 = *(const f16x8*)(tkS + (16 * nt + col) * KST + 32 + quad * 8);
            acc = __builtin_amdgcn_mfma_f32_16x16x32_f16(aq0, b0, acc, 0, 0, 0);
            acc = __builtin_amdgcn_mfma_f32_16x16x32_f16(aq1, b1, acc, 0, 0, 0);
            sc[nt] = acc;
        }
        #pragma unroll
        for (int r = 0; r < 4; r++) {
            float m = sc[0][r];
            #pragma unroll
            for (int nt = 1; nt < 6; nt++) m = fmaxf(m, sc[nt][r]);
            #pragma unroll
            for (int o = 1; o < 16; o <<= 1) m = fmaxf(m, __shfl_xor(m, o));
            float e[6]; float sum = 0.0f;
            #pragma unroll
            for (int nt = 0; nt < 6; nt++) { e[nt] = __expf(sc[nt][r] - m); sum += e[nt]; }
            #pragma unroll
            for (int o = 1; o < 16; o <<= 1) sum += __shfl_xor(sum, o);
            const float inv = 1.0f / sum;
            const int row = 16 * mt + quad * 4 + r;
            #pragma unroll
            for (int nt = 0; nt < 6; nt++)
                qB[row * KST + 16 * nt + col] = (_Float16)(e[nt] * inv);
        }
        f16x8 pa0 = *(const f16x8*)(qB + (16 * mt + col) * KST + quad * 8);
        f16x8 pa1 = *(const f16x8*)(qB + (16 * mt + col) * KST + 32 + quad * 8);
        f16x8 pa2 = *(const f16x8*)(qB + (16 * mt + col) * KST + 64 + quad * 8);
        #pragma unroll
        for (int nt = 0; nt < 4; nt++) {
            f32x4 acc = {0.f, 0.f, 0.f, 0.f};
            const _Float16* tvrow = tvT + (16 * nt + col) * KST;
            acc = __builtin_amdgcn_mfma_f32_16x16x32_f16(pa0, *(const f16x8*)(tvrow + quad * 8), acc, 0, 0, 0);
            acc = __builtin_amdgcn_mfma_f32_16x16x32_f16(pa1, *(const f16x8*)(tvrow + 32 + quad * 8), acc, 0, 0, 0);
            acc = __builtin_amdgcn_mfma_f32_16x16x32_f16(pa2, *(const f16x8*)(tvrow + 64 + quad * 8), acc, 0, 0, 0);
            #pragma unroll
            for (int r = 0; r < 4; r++)
                loB[(16 * mt + quad * 4 + r) * LOST2 + 16 * nt + col] = (_Float16)tanh_f(acc[r]);
        }
    }
    __syncthreads();

    for (int i = 0; i < 3; i++) {
        const int flat = w + 8 * i;
        const int mt = flat >> 2, nt = flat & 3;
        const int g = 16 * nt + col;
        f32x4 acc = {0.f, 0.f, 0.f, 0.f};
        #pragma unroll
        for (int kc = 0; kc < 2; kc++) {
            f16x8 a  = *(const f16x8*)(&loB[(16 * mt + col) * LOST2 + kc * 32 + quad * 8]);
            f16x8 bb = frag_from_f32(l2_wih + g * HH + kc * 32 + quad * 8);
            acc = __builtin_amdgcn_mfma_f32_16x16x32_f16(a, bb, acc, 0, 0, 0);
        }
        const float bg2 = l2_bih[g] + l2_bhh[g];
        #pragma unroll
        for (int r = 0; r < 4; r++) {
            const int row = 16 * mt + quad * 4 + r;
            xg2[(size_t)b * SS * HH + row * HH + g] = (_Float16)(acc[r] + bg2);
        }
    }
}

// ---------------- Kernel 4: batched MFMA LSTM2 + fc (unchanged) ----------------
__global__ __launch_bounds__(64) void k_lstm2(
    const _Float16* __restrict__ xg2,
    const float* __restrict__ l2_whh,
    const float* __restrict__ fc_w, const float* __restrict__ fc_b,
    float* __restrict__ out)
{
    __shared__ _Float16 xgS[8 * 16 * XGST];   // [s_l][n][72]
    __shared__ _Float16 hT[16 * HTST];        // [n][40], u>=16 zero (K-pad)

    const int bi = blockIdx.x;
    const int bg = bi * 16;
    const int lane = threadIdx.x;
    const int col = lane & 15, quad = lane >> 4;

    for (int i = lane; i < 16 * HTST / 2; i += 64) ((unsigned int*)hT)[i] = 0u;

    f16x8 wa[4];
    #pragma unroll
    for (int mt = 0; mt < 4; mt++) {
        f16x8 v;
        #pragma unroll
        for (int j = 0; j < 8; j++) v[j] = (_Float16)0.0f;
        if (quad < 2) {
            const float* src = l2_whh + (16 * mt + col) * H2 + quad * 8;
            #pragma unroll
            for (int j = 0; j < 8; j++) v[j] = (_Float16)src[j];
        }
        wa[mt] = v;
    }
    f16x8 fca;
    {
        f16x8 v;
        #pragma unroll
        for (int j = 0; j < 8; j++) v[j] = (_Float16)0.0f;
        if (quad < 2 && col < DD) {
            const float* src = fc_w + col * H2 + quad * 8;
            #pragma unroll
            for (int j = 0; j < 8; j++) v[j] = (_Float16)src[j];
        }
        fca = v;
    }
    float fcbr[4];
    #pragma unroll
    for (int r = 0; r < 4; r++) {
        const int d = quad * 4 + r;
        fcbr[r] = (d < DD) ? fc_b[d] : 0.0f;
    }

    float c[4] = {0.f, 0.f, 0.f, 0.f};
    f16x8 hfrag;
    #pragma unroll
    for (int j = 0; j < 8; j++) hfrag[j] = (_Float16)0.0f;

    for (int s0 = 0; s0 < SS; s0 += 8) {
        #pragma unroll
        for (int i = 0; i < 16; i++) {
            int fl = i * 64 + lane;
            int n = fl >> 6, r6 = fl & 63;
            int s_l = r6 >> 3, c8 = r6 & 7;
            f16x8 v = *(const f16x8*)(xg2 + ((size_t)(bg + n) * SS + s0 + s_l) * HH + c8 * 8);
            *(f16x8*)(&xgS[(s_l * 16 + n) * XGST + c8 * 8]) = v;
        }

        for (int sl = 0; sl < 8; sl++) {
            const int s = s0 + sl;
            f32x4 g[4];
            #pragma unroll
            for (int mt = 0; mt < 4; mt++) {
                f16x4 xi = *(const f16x4*)(&xgS[(sl * 16 + col) * XGST + 16 * mt + 4 * quad]);
                f32x4 acc;
                acc[0] = (float)xi[0]; acc[1] = (float)xi[1];
                acc[2] = (float)xi[2]; acc[3] = (float)xi[3];
                g[mt] = __builtin_amdgcn_mfma_f32_16x16x32_f16(wa[mt], hfrag, acc, 0, 0, 0);
            }
            f16x4 hq;
            #pragma unroll
            for (int r = 0; r < 4; r++) {
                float iv = sigm(g[0][r]);
                float fv = sigm(g[1][r]);
                float gv = tanh_f(g[2][r]);
                float ov = sigm(g[3][r]);
                c[r] = fv * c[r] + iv * gv;
                hq[r] = (_Float16)(ov * tanh_f(c[r]));
            }
            *(f16x4*)(&hT[col * HTST + 4 * quad]) = hq;
            hfrag = *(const f16x8*)(&hT[col * HTST + quad * 8]);
            f32x4 oz = {0.f, 0.f, 0.f, 0.f};
            f32x4 oacc = __builtin_amdgcn_mfma_f32_16x16x32_f16(fca, hfrag, oz, 0, 0, 0);
            float* op = out + ((size_t)(bg + col) * SS + s) * DD;
            #pragma unroll
            for (int r = 0; r < 4; r++) {
                const int d = quad * 4 + r;
                if (d < DD) op[d] = oacc[r] + fcbr[r];
            }
        }
    }
}

extern "C" void kernel_launch(void* const* d_in, const int* in_sizes, int n_in,
                              void* d_out, int out_size, void* d_ws, size_t ws_size,
                              hipStream_t stream) {
    const float* x     = (const float*)d_in[0];
    const float* fv_w  = (const float*)d_in[1];
    const float* fv_b  = (const float*)d_in[2];
    const float* fk_w  = (const float*)d_in[3];
    const float* fk_b  = (const float*)d_in[4];
    const float* fq_w  = (const float*)d_in[5];
    const float* fq_b  = (const float*)d_in[6];
    const float* l1f_wih = (const float*)d_in[7];
    const float* l1f_whh = (const float*)d_in[8];
    const float* l1f_bih = (const float*)d_in[9];
    const float* l1f_bhh = (const float*)d_in[10];
    const float* l1b_wih = (const float*)d_in[11];
    const float* l1b_whh = (const float*)d_in[12];
    const float* l1b_bih = (const float*)d_in[13];
    const float* l1b_bhh = (const float*)d_in[14];
    const float* tv_w  = (const float*)d_in[15];
    const float* tv_b  = (const float*)d_in[16];
    const float* tk_w  = (const float*)d_in[17];
    const float* tk_b  = (const float*)d_in[18];
    const float* tq_w  = (const float*)d_in[19];
    const float* tq_b  = (const float*)d_in[20];
    const float* l2_wih = (const float*)d_in[21];
    const float* l2_whh = (const float*)d_in[22];
    const float* l2_bih = (const float*)d_in[23];
    const float* l2_bhh = (const float*)d_in[24];
    const float* fc_w  = (const float*)d_in[25];
    const float* fc_b  = (const float*)d_in[26];

    float* fa = (float*)d_ws;                              // B*S*D fp32
    _Float16* hf = (_Float16*)(fa + (size_t)BB * SS * DD); // B*S*H f16
    _Float16* hb = hf + (size_t)BB * SS * HH;              // B*S*H f16
    _Float16* xg2 = hf;  // overlay: k_attn block b reads hf[b] first, writes xg2[b] last

    k_feat<<<BB, 256, 0, stream>>>(x, fv_w, fv_b, fk_w, fk_b, fq_w, fq_b, fa);
    k_bilstm<<<256, 256, 0, stream>>>(fa,
        l1f_wih, l1f_whh, l1f_bih, l1f_bhh,
        l1b_wih, l1b_whh, l1b_bih, l1b_bhh, hf, hb);
    k_attn<<<BB, 512, 0, stream>>>(hf, hb,
        tv_w, tv_b, tk_w, tk_b, tq_w, tq_b,
        l2_wih, l2_bih, l2_bhh, xg2);
    k_lstm2<<<128, 64, 0, stream>>>(xg2, l2_whh, fc_w, fc_b, (float*)d_out);
}